// Round 10
// baseline (282.798 us; speedup 1.0000x reference)
//
#include <hip/hip_runtime.h>

// B=2, S=2048, D=1024, H=16, DK=64
// out = attn_mean @ vs @ Wo  (Wv shared across heads => mean_h(attn_h @ vs) = attn_mean @ vs)
// attn_mean[b,s,t] = (1/H) sum_h exp(score)/denom  -- no max-subtraction (scores bounded ~|2.5|)
// qs/ks layout: [b*S+s][h*64+dk]  (concatenated-head GEMM output)
// All LDS tiles are FRAGMENT-MAJOR: 16B-unit index = tile*64 + quad*16 + l15
//   -> reader addr = tilebase + lane*16B, conflict-free for ds_read_b128.
// r10: OCCUPANCY 2x at constant per-CU work. Eliminated for k_attn's 43us: spills(r1),
// LDS-BW(r7), ILP(r6), HBM/L3 BW(r8), staging order(r9), bank conflicts(0). Remaining:
// grid-imposed 16 waves/CU (512 blocks = 2/CU). Now: s-tile 64, grid 1024, 4 blocks/CU
// -> 32 waves/CU. Per-CU LDS reads / VALU / MFMA unchanged; staging doubles (L2-local
// via extended XCD swizzle, per-XCD working set still 4MB). acc[4], VGPR ~<=64.
#define B_ 2
#define S_ 2048
#define D_ 1024
#define H_ 16
#define DK_ 64

typedef __bf16 bf8 __attribute__((ext_vector_type(8)));
typedef float f4 __attribute__((ext_vector_type(4)));
typedef unsigned short u16x8 __attribute__((ext_vector_type(8)));

__device__ __forceinline__ unsigned short f2bf_bits(float f) {
  unsigned int u = __float_as_uint(f);
  return (unsigned short)((u + 0x7fffu + ((u >> 16) & 1u)) >> 16);
}

__device__ __forceinline__ bf8 pack_bf8(f4 lo, f4 hi) {
  u16x8 u;
  u[0] = f2bf_bits(lo[0]); u[1] = f2bf_bits(lo[1]);
  u[2] = f2bf_bits(lo[2]); u[3] = f2bf_bits(lo[3]);
  u[4] = f2bf_bits(hi[0]); u[5] = f2bf_bits(hi[1]);
  u[6] = f2bf_bits(hi[2]); u[7] = f2bf_bits(hi[3]);
  union { u16x8 u; bf8 b; } x; x.u = u; return x.b;
}

__device__ __forceinline__ bf8 ldb(const unsigned short* p) {
  return *reinterpret_cast<const bf8*>(p);
}

__device__ __forceinline__ void stage16(const void* g, void* l) {
  __builtin_amdgcn_global_load_lds(
      (const __attribute__((address_space(1))) void*)g,
      (__attribute__((address_space(3))) void*)l, 16, 0, 0);
}

#define MFMA(a, b, c) __builtin_amdgcn_mfma_f32_16x16x32_bf16((a), (b), (c), 0, 0, 0)

// ---- merged prep: cast q,k -> bf16 rows; LDS-tiled transpose-cast weights ----
// blocks 0..4095: cast q/k | 4096..4351: wq/wk 64x64 tiles | 4352..4367: wv | 4368..4383: wo
__global__ void k_prep(const float* __restrict__ q, const float* __restrict__ k,
                       const float* __restrict__ wq, const float* __restrict__ wk,
                       const float* __restrict__ wv, const float* __restrict__ wo,
                       unsigned short* __restrict__ qb, unsigned short* __restrict__ kb,
                       unsigned short* __restrict__ wqt, unsigned short* __restrict__ wkt,
                       unsigned short* __restrict__ wvt, unsigned short* __restrict__ wot) {
  __shared__ float tl[64 * 65];
  int bid = blockIdx.x, tid = threadIdx.x;
  const int rr = tid >> 6, cc = tid & 63;
  if (bid < 4096) {
    int which = bid >> 11;
    long i = ((long)(bid & 2047) * 256 + tid) * 8;
    const float* src = which ? k : q;
    unsigned short* dst = which ? kb : qb;
    f4 lo = *reinterpret_cast<const f4*>(src + i);
    f4 hi = *reinterpret_cast<const f4*>(src + i + 4);
    *reinterpret_cast<bf8*>(dst + i) = pack_bf8(lo, hi);
  } else if (bid < 4352) {
    // Wq/Wk [h][d][n=dk] -> [h][n][d], 64x64 f32 tile via LDS (coalesced both ways)
    int blk = bid - 4096;
    int h = blk >> 4, d0 = (blk & 15) * 64;
    for (int m = 0; m < 2; ++m) {
      const float* src = m ? wk : wq;
      unsigned short* dst = m ? wkt : wqt;
      if (m) __syncthreads();
#pragma unroll
      for (int it = 0; it < 16; ++it) {
        int d = it * 4 + rr;
        tl[cc * 65 + d] = src[(long)h * 65536 + (d0 + d) * 64 + cc];
      }
      __syncthreads();
#pragma unroll
      for (int it = 0; it < 16; ++it) {
        int n = it * 4 + rr;
        dst[(long)h * 65536 + n * 1024 + d0 + cc] = f2bf_bits(tl[n * 65 + cc]);
      }
    }
  } else if (bid < 4368) {
    // Wv [d][n=dk] -> [n][d]
    int d0 = (bid - 4352) * 64;
#pragma unroll
    for (int it = 0; it < 16; ++it) {
      int d = it * 4 + rr;
      tl[cc * 65 + d] = wv[(long)(d0 + d) * 64 + cc];
    }
    __syncthreads();
#pragma unroll
    for (int it = 0; it < 16; ++it) {
      int n = it * 4 + rr;
      wvt[(long)n * 1024 + d0 + cc] = f2bf_bits(tl[n * 65 + cc]);
    }
  } else {
    // Wo [kk][dd] -> [dd][kk]
    int d0 = (bid - 4368) * 64;
#pragma unroll
    for (int it = 0; it < 16; ++it) {
      int kk = it * 4 + rr;
      tl[cc * 65 + kk] = wo[(long)kk * 1024 + d0 + cc];   // tl[ddl][kk]
    }
    __syncthreads();
#pragma unroll
    for (int it = 0; it < 16; ++it) {
      int ddl = it * 4 + rr;
      wot[(long)(d0 + ddl) * 64 + cc] = f2bf_bits(tl[ddl * 65 + cc]);
    }
  }
}

// ---- GEMM: C[4096][1024] = X @ W^T, 128x128 tile, BK=32, fragment-major LDS (m97 geometry) ----
// grid (32 m-tiles, 8 n-tiles, which), block 256 (4 waves 2x2; wave = 64m x 64n, 4x4 MFMA)
__global__ __launch_bounds__(256) void k_gemm_qk(
    const unsigned short* __restrict__ qb, const unsigned short* __restrict__ kb,
    const unsigned short* __restrict__ wqt, const unsigned short* __restrict__ wkt,
    unsigned short* __restrict__ qsb, unsigned short* __restrict__ ksb) {
  __shared__ unsigned short lds[8192];          // A 8 tiles @0 (tile*512), B 8 tiles @4096
  const int tid = threadIdx.x, wave = tid >> 6, lane = tid & 63;
  const int l15 = lane & 15, quad = lane >> 4;
  const int m0 = blockIdx.x * 128, n0 = blockIdx.y * 128;
  const int which = blockIdx.z;
  const unsigned short* A = which ? kb : qb;
  const unsigned short* W = which ? wkt : wqt;
  unsigned short* C = which ? ksb : qsb;
  const float scale = which ? 1.0f : 0.18033688011112042f;  // log2(e)/8 folded into qs
  const int wr = wave >> 1, wc = wave & 1;

  f4 acc[4][4];
#pragma unroll
  for (int i = 0; i < 4; ++i)
#pragma unroll
    for (int j = 0; j < 4; ++j) acc[i][j] = f4{0.f, 0.f, 0.f, 0.f};

  // staging decode: u = i*256+tid; tile=u>>6 (st + i*4), quad=(u>>4)&3, l15=u&15
  const int sl15 = tid & 15, squad = (tid >> 4) & 3, st = tid >> 6;
  const unsigned short* gA = A + (long)(m0 + st * 16 + sl15) * D_ + squad * 8;
  const unsigned short* gB = W + (long)(n0 + st * 16 + sl15) * D_ + squad * 8;

  for (int k0 = 0; k0 < D_; k0 += 32) {
    stage16(gA + k0, lds + tid * 8);                       // A tiles 0..3
    stage16(gA + 64 * D_ + k0, lds + 2048 + tid * 8);      // A tiles 4..7
    stage16(gB + k0, lds + 4096 + tid * 8);                // B tiles 0..3
    stage16(gB + 64 * D_ + k0, lds + 6144 + tid * 8);      // B tiles 4..7
    __syncthreads();
    bf8 aF[4], bF[4];
#pragma unroll
    for (int mi = 0; mi < 4; ++mi)
      aF[mi] = ldb(lds + (wr * 4 + mi) * 512 + lane * 8);
#pragma unroll
    for (int ni = 0; ni < 4; ++ni)
      bF[ni] = ldb(lds + 4096 + (wc * 4 + ni) * 512 + lane * 8);
#pragma unroll
    for (int mi = 0; mi < 4; ++mi)
#pragma unroll
      for (int ni = 0; ni < 4; ++ni)
        acc[mi][ni] = MFMA(aF[mi], bF[ni], acc[mi][ni]);
    __syncthreads();
  }
#pragma unroll
  for (int mi = 0; mi < 4; ++mi)
#pragma unroll
    for (int r = 0; r < 4; ++r) {
      long row = m0 + wr * 64 + mi * 16 + quad * 4 + r;
#pragma unroll
      for (int ni = 0; ni < 4; ++ni)
        C[row * D_ + n0 + wc * 64 + ni * 16 + l15] = f2bf_bits(acc[mi][ni][r] * scale);
    }
}

// ---- V projection split-K: partial[kc][row][64] f32, kc chunk = 256 ----
// grid (64 rowgroups of 64, 4 kc), block 256
__global__ __launch_bounds__(256) void k_pv(
    const float* __restrict__ v, const unsigned short* __restrict__ wvt,
    float* __restrict__ pv) {
  const int tid = threadIdx.x, wave = tid >> 6, lane = tid & 63;
  const int l15 = lane & 15, quad = lane >> 4;
  const int rg = blockIdx.x, kc = blockIdx.y;
  const int row0 = rg * 64 + wave * 16;
  const float* arow = v + (long)(row0 + l15) * D_ + kc * 256 + quad * 8;
  const unsigned short* wbase = wvt + kc * 256 + quad * 8;
  f4 acc[4];
  for (int i = 0; i < 4; ++i) acc[i] = f4{0.f, 0.f, 0.f, 0.f};
  for (int k0 = 0; k0 < 256; k0 += 32) {
    f4 alo = *reinterpret_cast<const f4*>(arow + k0);
    f4 ahi = *reinterpret_cast<const f4*>(arow + k0 + 4);
    bf8 a = pack_bf8(alo, ahi);
#pragma unroll
    for (int i = 0; i < 4; ++i) {
      bf8 bf = ldb(wbase + (long)(i * 16 + l15) * D_ + k0);
      acc[i] = MFMA(a, bf, acc[i]);
    }
  }
#pragma unroll
  for (int i = 0; i < 4; ++i)
#pragma unroll
    for (int r = 0; r < 4; ++r)
      pv[((long)kc * 4096 + row0 + quad * 4 + r) * 64 + i * 16 + l15] = acc[i][r];
}

// reduce 4 k-partials -> vst[b][dk][t] bf16 (writes coalesced over t)
__global__ void k_vred(const float* __restrict__ pv, unsigned short* __restrict__ vst) {
  int e = blockIdx.x * 256 + threadIdx.x;      // e = (b*64+dk)*2048 + t
  int t = e & 2047, dk = (e >> 11) & 63, b = e >> 17;
  long row = (long)b * S_ + t;
  float s = pv[row * 64 + dk] + pv[(4096 + row) * 64 + dk] +
            pv[(8192 + row) * 64 + dk] + pv[(12288 + row) * 64 + dk];
  vst[e] = f2bf_bits(s);
}

// ---- pass 1: recip[b,h,s] = 1/(H * sum_t exp2(qs.ks)) ----
// 1D grid 1024, block 512 (8 waves split 4s x 2t); s-tile 64 -> 4 blocks/CU, 32 waves/CU.
// XCD decode: xcd=n&7 -> b=xcd>>2, h-group=xcd&3; slot: h-low + stile. Per-XCD working
// set: 4 h-cols K (1MB) + their Q (1MB) = 2MB in L2. 2-phase dbuf; wt-halves combined
// via small LDS reduce.
__global__ __launch_bounds__(512) void k_denom(
    const unsigned short* __restrict__ qsb, const unsigned short* __restrict__ ksb,
    float* __restrict__ recip) {
  __shared__ unsigned short lds[16384];         // 2 x (128 t-rows x 64 dk), fragment-major
  __shared__ float red[2][4][16];               // [wt][ws][row16]
  const int tid = threadIdx.x, wave = tid >> 6, lane = tid & 63;
  const int l15 = lane & 15, quad = lane >> 4;
  const int ws = wave >> 1, wt = wave & 1;
  const int n = blockIdx.x, xcd = n & 7, slot = n >> 3;   // slot 0..127
  const int b = xcd >> 2;
  const int h = ((xcd & 3) << 2) | (slot & 3);
  const int stile = slot >> 2;                            // 0..31 (tiles of 64 rows)
  const int s0 = stile * 64 + ws * 16;

  const unsigned short* qrow = qsb + ((long)(b * S_) + s0 + l15) * D_ + h * 64 + quad * 8;
  bf8 a0 = ldb(qrow);
  bf8 a1 = ldb(qrow + 32);

  // staging decode (full 128-t tile for head h): stt=(tid>>6)&7
  const int sl15 = tid & 15, squad = (tid >> 4) & 3, stt = (tid >> 6) & 7;
  const unsigned short* g0 =
      ksb + ((long)(b * S_) + stt * 16 + sl15) * D_ + h * 64 + squad * 8;

  // prologue: stage tile 0 into buf0
  stage16(g0, lds + tid * 8);
  stage16(g0 + 32, lds + 4096 + tid * 8);
  asm volatile("s_waitcnt vmcnt(0)" ::: "memory");
  __builtin_amdgcn_s_barrier();
  int cur = 0;

  f4 sum = f4{0.f, 0.f, 0.f, 0.f};
  for (int it = 0; it < 16; ++it) {
    if (it + 1 < 16) {
      const unsigned short* gn = g0 + (long)(it + 1) * 128 * D_;
      unsigned short* nb = lds + (cur ^ 1) * 8192;
      stage16(gn, nb + tid * 8);
      stage16(gn + 32, nb + 4096 + tid * 8);
    }
    // wave's t-half: t-frags wt*4 .. wt*4+3 (dk-lo at +0, dk-hi at +4096)
    const unsigned short* base = lds + cur * 8192 + wt * 2048;
    __builtin_amdgcn_s_setprio(1);
#pragma unroll
    for (int tt = 0; tt < 4; ++tt) {
      bf8 b0 = ldb(base + tt * 512 + lane * 8);
      bf8 b1 = ldb(base + 4096 + tt * 512 + lane * 8);
      f4 d = f4{0.f, 0.f, 0.f, 0.f};
      d = MFMA(a0, b0, d);
      d = MFMA(a1, b1, d);
#pragma unroll
      for (int r = 0; r < 4; ++r) sum[r] += __builtin_amdgcn_exp2f(d[r]);
    }
    __builtin_amdgcn_s_setprio(0);
    if (it + 1 < 16) {
      asm volatile("s_waitcnt vmcnt(0)" ::: "memory");
      __builtin_amdgcn_s_barrier();
      cur ^= 1;
    }
  }
#pragma unroll
  for (int m = 1; m < 16; m <<= 1) {
#pragma unroll
    for (int r = 0; r < 4; ++r) sum[r] += __shfl_xor(sum[r], m, 64);
  }
  if (l15 == 0) {
#pragma unroll
    for (int r = 0; r < 4; ++r) red[wt][ws][quad * 4 + r] = sum[r];
  }
  __syncthreads();
  if (tid < 64) {
    int wsi = tid >> 4, r16 = tid & 15;
    float ssum = red[0][wsi][r16] + red[1][wsi][r16];
    recip[(long)(b * H_ + h) * S_ + stile * 64 + tid] = 1.0f / (16.0f * ssum);
  }
}

// ---- pass 2: attn_mean[b,s,t] = sum_h recip[b,h,s]*exp2(score) ----
// 1D grid 1024, block 512 (8 waves 4s x 2t); s-tile 64, t-chunk 128 -> 4 blocks/CU,
// 32 waves/CU (2x r9). Per-CU LDS reads / VALU / MFMA unchanged; staging 2x but
// XCD-local: per-XCD 16 stiles x 8 tchunks -> Q 2MB + K 2MB = 4MB = one L2.
// Retains: 2-phase dbuf, Q-frag register prefetch before stage16 (sched_barrier),
// setprio around compute.
__global__ __launch_bounds__(512) void k_attn(
    const unsigned short* __restrict__ qsb, const unsigned short* __restrict__ ksb,
    const float* __restrict__ recip, float* __restrict__ am) {
  __shared__ unsigned short lds[16384];         // 2 x (128 t-rows x 64 dk) per head
  const int tid = threadIdx.x, wave = tid >> 6, lane = tid & 63;
  const int l15 = lane & 15, quad = lane >> 4;
  const int ws = wave >> 1, wt = wave & 1;
  const int n = blockIdx.x, xcd = n & 7, slot = n >> 3;   // slot 0..127
  const int b = xcd >> 2;
  const int tchunk = ((xcd & 1) << 3) | (slot & 7);       // 0..15 (128 t each)
  const int stile = (((xcd >> 1) & 1) << 4) | (slot >> 3); // 0..31 (64 s each)
  const int s0 = stile * 64 + ws * 16;
  const int t0c = tchunk * 128;

  f4 acc[4];
#pragma unroll
  for (int tt = 0; tt < 4; ++tt) acc[tt] = f4{0.f, 0.f, 0.f, 0.f};

  const unsigned short* qbase = qsb + ((long)(b * S_) + s0 + l15) * D_ + quad * 8;
  // staging decode (full 128-t tile): stt=(tid>>6)&7
  const int sl15 = tid & 15, squad = (tid >> 4) & 3, stt = (tid >> 6) & 7;
  const unsigned short* g0 =
      ksb + ((long)(b * S_) + t0c + stt * 16 + sl15) * D_ + squad * 8;
  const float* rbase = recip + (long)(b * H_) * S_ + s0 + quad * 4;

  // prologue: stage head 0 into buf0; load head 0's Q-frags + recip
  stage16(g0, lds + tid * 8);
  stage16(g0 + 32, lds + 4096 + tid * 8);
  bf8 a0 = ldb(qbase);
  bf8 a1 = ldb(qbase + 32);
  f4 rp = *reinterpret_cast<const f4*>(rbase);
  asm volatile("s_waitcnt vmcnt(0)" ::: "memory");
  __builtin_amdgcn_s_barrier();
  int cur = 0;

  for (int h = 0; h < H_; ++h) {
    bf8 a0n, a1n;
    f4 rpn;
    if (h + 1 < H_) {
      // register prefetch for head h+1, issued BEFORE the staging (in-order vmcnt)
      a0n = ldb(qbase + (h + 1) * 64);
      a1n = ldb(qbase + (h + 1) * 64 + 32);
      rpn = *reinterpret_cast<const f4*>(rbase + (long)(h + 1) * S_);
      __builtin_amdgcn_sched_barrier(0);        // pin: reg loads above, staging below
      const unsigned short* gn = g0 + (h + 1) * 64;
      unsigned short* nb = lds + (cur ^ 1) * 8192;
      stage16(gn, nb + tid * 8);
      stage16(gn + 32, nb + 4096 + tid * 8);
    }
    // wave's t-half: t-frags wt*4 .. wt*4+3
    const unsigned short* base = lds + cur * 8192 + wt * 2048;
    __builtin_amdgcn_s_setprio(1);
#pragma unroll
    for (int tt = 0; tt < 4; ++tt) {
      bf8 b0 = ldb(base + tt * 512 + lane * 8);
      bf8 b1 = ldb(base + 4096 + tt * 512 + lane * 8);
      f4 d = f4{0.f, 0.f, 0.f, 0.f};
      d = MFMA(a0, b0, d);
      d = MFMA(a1, b1, d);
#pragma unroll
      for (int r = 0; r < 4; ++r) acc[tt][r] += rp[r] * __builtin_amdgcn_exp2f(d[r]);
    }
    __builtin_amdgcn_s_setprio(0);
    if (h + 1 < H_) {
      asm volatile("s_waitcnt vmcnt(0)" ::: "memory");
      __builtin_amdgcn_s_barrier();
      cur ^= 1;
      a0 = a0n;
      a1 = a1n;
      rp = rpn;
    }
  }
  // rows: s0 + quad*4 + r; cols: t0c + wt*64 + tt*16 + l15
  float* obase = am + ((long)b * S_ + s0 + quad * 4) * S_ + t0c + wt * 64 + l15;
#pragma unroll
  for (int tt = 0; tt < 4; ++tt)
#pragma unroll
    for (int r = 0; r < 4; ++r) obase[(long)r * S_ + tt * 16] = acc[tt][r];
}

// ---- head split-K: ph[kc][row][64] f32 = am-chunk @ vs-chunk, kc chunk = 512 t ----
// grid (64 rowgroups, 4 kc), block 256
__global__ __launch_bounds__(256) void k_hpart(
    const float* __restrict__ am, const unsigned short* __restrict__ vst,
    float* __restrict__ ph) {
  const int tid = threadIdx.x, wave = tid >> 6, lane = tid & 63;
  const int l15 = lane & 15, quad = lane >> 4;
  const int rg = blockIdx.x, kc = blockIdx.y;
  const int row0 = rg * 64 + wave * 16;
  const int b = row0 >> 11;
  const float* arow = am + (long)(row0 + l15) * S_ + kc * 512 + quad * 8;
  const unsigned short* vb = vst + (long)b * DK_ * S_ + kc * 512 + quad * 8;
  f4 acc[4];
  for (int i = 0; i < 4; ++i) acc[i] = f4{0.f, 0.f, 0.f, 0.f};
  for (int t0 = 0; t0 < 512; t0 += 32) {
    f4 alo = *reinterpret_cast<const f4*>(arow + t0);
    f4 ahi = *reinterpret_cast<const f4*>(arow + t0 + 4);
    bf8 a = pack_bf8(alo, ahi);
#pragma unroll
    for (int i = 0; i < 4; ++i) {
      bf8 bf = ldb(vb + (long)(i * 16 + l15) * S_ + t0);
      acc[i] = MFMA(a, bf, acc[i]);
    }
  }
#pragma unroll
  for (int i = 0; i < 4; ++i)
#pragma unroll
    for (int r = 0; r < 4; ++r)
      ph[((long)kc * 4096 + row0 + quad * 4 + r) * 64 + i * 16 + l15] = acc[i][r];
}

// reduce -> headb bf16 [row][64] (fully coalesced)
__global__ void k_hred(const float* __restrict__ ph, unsigned short* __restrict__ headb) {
  int e = blockIdx.x * 256 + threadIdx.x;      // e = row*64 + dk
  float s = ph[e] + ph[e + 4096 * 64] + ph[e + 2 * 4096 * 64] + ph[e + 3 * 4096 * 64];
  headb[e] = f2bf_bits(s);
}

// ---- out = head @ Wo ----
// grid (8 d-chunks of 128, 32 s-tiles of 64, B), block 256
__global__ __launch_bounds__(256) void k_out(
    const unsigned short* __restrict__ head, const unsigned short* __restrict__ wot,
    float* __restrict__ out) {
  const int tid = threadIdx.x, wave = tid >> 6, lane = tid & 63;
  const int l15 = lane & 15, quad = lane >> 4;
  const int dchunk = blockIdx.x, stile = blockIdx.y, b = blockIdx.z;
  const int s0 = stile * 64 + wave * 16;
  const int n0 = dchunk * 128;
  const unsigned short* hrow = head + ((long)b * S_ + s0 + l15) * DK_ + quad * 8;
  bf8 a0 = ldb(hrow);
  bf8 a1 = ldb(hrow + 32);
  const unsigned short* wb = wot + quad * 8;
  float* obase = out + ((long)b * S_ + s0 + quad * 4) * D_ + n0 + l15;
#pragma unroll
  for (int i = 0; i < 8; ++i) {
    const unsigned short* wp = wb + (long)(n0 + i * 16 + l15) * DK_;
    bf8 b0 = ldb(wp);
    bf8 b1 = ldb(wp + 32);
    f4 d = f4{0.f, 0.f, 0.f, 0.f};
    d = MFMA(a0, b0, d);
    d = MFMA(a1, b1, d);
#pragma unroll
    for (int r = 0; r < 4; ++r) obase[(long)r * D_ + i * 16] = d[r];
  }
}

extern "C" void kernel_launch(void* const* d_in, const int* in_sizes, int n_in,
                              void* d_out, int out_size, void* d_ws, size_t ws_size,
                              hipStream_t stream) {
  const float* q  = (const float*)d_in[0];
  const float* k  = (const float*)d_in[1];
  const float* v  = (const float*)d_in[2];
  const float* Wq = (const float*)d_in[3];
  const float* Wk = (const float*)d_in[4];
  const float* Wv = (const float*)d_in[5];
  const float* Wo = (const float*)d_in[6];

  float* out = (float*)d_out;                       // [B,S,D] = 4,194,304 f32
  float* am  = out + (long)B_ * S_ * D_;            // [B,S,S] = 8,388,608 f32

  // workspace (~22.5 MB)
  unsigned short* qsb  = (unsigned short*)d_ws;     // [4096][1024]
  unsigned short* ksb  = qsb + 4194304;
  unsigned short* wqt  = ksb + 4194304;             // [1024][1024]
  unsigned short* wkt  = wqt + 1048576;
  unsigned short* wvt  = wkt + 1048576;             // [64][1024]
  unsigned short* wot  = wvt + 65536;               // [1024][64]
  unsigned short* vst  = wot + 65536;               // [B][64][S]
  unsigned short* headb= vst + 262144;              // [4096][64]
  float* recip = (float*)(headb + 262144);          // [B*H*S]

  // bf16 q,k copies live in the am region of d_out (dead before k_attn writes am)
  unsigned short* qb = (unsigned short*)am;         // [4096][1024]
  unsigned short* kb = qb + 4194304;
  // split-K f32 partials [4][4096][64] live in the out region (dead until k_out)
  float* part = out;

  k_prep<<<4384, 256, 0, stream>>>(q, k, Wq, Wk, Wv, Wo, qb, kb, wqt, wkt, wvt, wot);
  k_gemm_qk<<<dim3(32, 8, 2), 256, 0, stream>>>(qb, kb, wqt, wkt, qsb, ksb);
  k_pv<<<dim3(64, 4), 256, 0, stream>>>(v, wvt, part);
  k_vred<<<1024, 256, 0, stream>>>(part, vst);
  k_denom<<<1024, 512, 0, stream>>>(qsb, ksb, recip);
  k_attn<<<1024, 512, 0, stream>>>(qsb, ksb, recip, am);
  k_hpart<<<dim3(64, 4), 256, 0, stream>>>(am, vst, part);
  k_hred<<<1024, 256, 0, stream>>>(part, headb);
  k_out<<<dim3(8, 32, 2), 256, 0, stream>>>(headb, wot, out);
}

// Round 11
// 241.777 us; speedup vs baseline: 1.1697x; 1.1697x over previous
//
#include <hip/hip_runtime.h>

// B=2, S=2048, D=1024, H=16, DK=64
// out = attn_mean @ vs @ Wo  (Wv shared across heads => mean_h(attn_h @ vs) = attn_mean @ vs)
// attn_mean[b,s,t] = (1/H) sum_h exp(score)/denom  -- no max-subtraction (scores bounded ~|2.5|)
// qs/ks layout: [b*S+s][h*64+dk]  (concatenated-head GEMM output)
// All LDS tiles are FRAGMENT-MAJOR: 16B-unit index = tile*64 + quad*16 + l15
//   -> reader addr = tilebase + lane*16B, conflict-free for ds_read_b128.
// r11 = r9 (best, 240.0us: XCD swizzle + reg prefetch) + T4 COUNTED VMCNT, 3-buffer LDS
// rotation. All prior rounds drained vmcnt(0) per head-iteration (the T4 anti-pattern):
// staging got only one compute phase (~400cy) to cover an ~800cy L2->LDS round trip,
// serializing the remainder x16 heads. Now: stage head h+2 while computing h; end-of-iter
// wait is vmcnt(5) (= regs(h+1)[3] + stages(h+2)[2] allowed in flight), never 0 in-loop.
// Eliminated: spills(r1), LDS-BW(r7), ILP(r6), HBM/L3 BW(r8), TLP/occupancy(r1,r10).
#define B_ 2
#define S_ 2048
#define D_ 1024
#define H_ 16
#define DK_ 64

typedef __bf16 bf8 __attribute__((ext_vector_type(8)));
typedef float f4 __attribute__((ext_vector_type(4)));
typedef unsigned short u16x8 __attribute__((ext_vector_type(8)));

__device__ __forceinline__ unsigned short f2bf_bits(float f) {
  unsigned int u = __float_as_uint(f);
  return (unsigned short)((u + 0x7fffu + ((u >> 16) & 1u)) >> 16);
}

__device__ __forceinline__ bf8 pack_bf8(f4 lo, f4 hi) {
  u16x8 u;
  u[0] = f2bf_bits(lo[0]); u[1] = f2bf_bits(lo[1]);
  u[2] = f2bf_bits(lo[2]); u[3] = f2bf_bits(lo[3]);
  u[4] = f2bf_bits(hi[0]); u[5] = f2bf_bits(hi[1]);
  u[6] = f2bf_bits(hi[2]); u[7] = f2bf_bits(hi[3]);
  union { u16x8 u; bf8 b; } x; x.u = u; return x.b;
}

__device__ __forceinline__ bf8 ldb(const unsigned short* p) {
  return *reinterpret_cast<const bf8*>(p);
}

__device__ __forceinline__ void stage16(const void* g, void* l) {
  __builtin_amdgcn_global_load_lds(
      (const __attribute__((address_space(1))) void*)g,
      (__attribute__((address_space(3))) void*)l, 16, 0, 0);
}

#define MFMA(a, b, c) __builtin_amdgcn_mfma_f32_16x16x32_bf16((a), (b), (c), 0, 0, 0)

// ---- merged prep: cast q,k -> bf16 rows; LDS-tiled transpose-cast weights ----
// blocks 0..4095: cast q/k | 4096..4351: wq/wk 64x64 tiles | 4352..4367: wv | 4368..4383: wo
__global__ void k_prep(const float* __restrict__ q, const float* __restrict__ k,
                       const float* __restrict__ wq, const float* __restrict__ wk,
                       const float* __restrict__ wv, const float* __restrict__ wo,
                       unsigned short* __restrict__ qb, unsigned short* __restrict__ kb,
                       unsigned short* __restrict__ wqt, unsigned short* __restrict__ wkt,
                       unsigned short* __restrict__ wvt, unsigned short* __restrict__ wot) {
  __shared__ float tl[64 * 65];
  int bid = blockIdx.x, tid = threadIdx.x;
  const int rr = tid >> 6, cc = tid & 63;
  if (bid < 4096) {
    int which = bid >> 11;
    long i = ((long)(bid & 2047) * 256 + tid) * 8;
    const float* src = which ? k : q;
    unsigned short* dst = which ? kb : qb;
    f4 lo = *reinterpret_cast<const f4*>(src + i);
    f4 hi = *reinterpret_cast<const f4*>(src + i + 4);
    *reinterpret_cast<bf8*>(dst + i) = pack_bf8(lo, hi);
  } else if (bid < 4352) {
    // Wq/Wk [h][d][n=dk] -> [h][n][d], 64x64 f32 tile via LDS (coalesced both ways)
    int blk = bid - 4096;
    int h = blk >> 4, d0 = (blk & 15) * 64;
    for (int m = 0; m < 2; ++m) {
      const float* src = m ? wk : wq;
      unsigned short* dst = m ? wkt : wqt;
      if (m) __syncthreads();
#pragma unroll
      for (int it = 0; it < 16; ++it) {
        int d = it * 4 + rr;
        tl[cc * 65 + d] = src[(long)h * 65536 + (d0 + d) * 64 + cc];
      }
      __syncthreads();
#pragma unroll
      for (int it = 0; it < 16; ++it) {
        int n = it * 4 + rr;
        dst[(long)h * 65536 + n * 1024 + d0 + cc] = f2bf_bits(tl[n * 65 + cc]);
      }
    }
  } else if (bid < 4368) {
    // Wv [d][n=dk] -> [n][d]
    int d0 = (bid - 4352) * 64;
#pragma unroll
    for (int it = 0; it < 16; ++it) {
      int d = it * 4 + rr;
      tl[cc * 65 + d] = wv[(long)(d0 + d) * 64 + cc];
    }
    __syncthreads();
#pragma unroll
    for (int it = 0; it < 16; ++it) {
      int n = it * 4 + rr;
      wvt[(long)n * 1024 + d0 + cc] = f2bf_bits(tl[n * 65 + cc]);
    }
  } else {
    // Wo [kk][dd] -> [dd][kk]
    int d0 = (bid - 4368) * 64;
#pragma unroll
    for (int it = 0; it < 16; ++it) {
      int kk = it * 4 + rr;
      tl[cc * 65 + kk] = wo[(long)kk * 1024 + d0 + cc];   // tl[ddl][kk]
    }
    __syncthreads();
#pragma unroll
    for (int it = 0; it < 16; ++it) {
      int ddl = it * 4 + rr;
      wot[(long)(d0 + ddl) * 64 + cc] = f2bf_bits(tl[ddl * 65 + cc]);
    }
  }
}

// ---- GEMM: C[4096][1024] = X @ W^T, 128x128 tile, BK=32, fragment-major LDS (m97 geometry) ----
// grid (32 m-tiles, 8 n-tiles, which), block 256 (4 waves 2x2; wave = 64m x 64n, 4x4 MFMA)
__global__ __launch_bounds__(256) void k_gemm_qk(
    const unsigned short* __restrict__ qb, const unsigned short* __restrict__ kb,
    const unsigned short* __restrict__ wqt, const unsigned short* __restrict__ wkt,
    unsigned short* __restrict__ qsb, unsigned short* __restrict__ ksb) {
  __shared__ unsigned short lds[8192];          // A 8 tiles @0 (tile*512), B 8 tiles @4096
  const int tid = threadIdx.x, wave = tid >> 6, lane = tid & 63;
  const int l15 = lane & 15, quad = lane >> 4;
  const int m0 = blockIdx.x * 128, n0 = blockIdx.y * 128;
  const int which = blockIdx.z;
  const unsigned short* A = which ? kb : qb;
  const unsigned short* W = which ? wkt : wqt;
  unsigned short* C = which ? ksb : qsb;
  const float scale = which ? 1.0f : 0.18033688011112042f;  // log2(e)/8 folded into qs
  const int wr = wave >> 1, wc = wave & 1;

  f4 acc[4][4];
#pragma unroll
  for (int i = 0; i < 4; ++i)
#pragma unroll
    for (int j = 0; j < 4; ++j) acc[i][j] = f4{0.f, 0.f, 0.f, 0.f};

  // staging decode: u = i*256+tid; tile=u>>6 (st + i*4), quad=(u>>4)&3, l15=u&15
  const int sl15 = tid & 15, squad = (tid >> 4) & 3, st = tid >> 6;
  const unsigned short* gA = A + (long)(m0 + st * 16 + sl15) * D_ + squad * 8;
  const unsigned short* gB = W + (long)(n0 + st * 16 + sl15) * D_ + squad * 8;

  for (int k0 = 0; k0 < D_; k0 += 32) {
    stage16(gA + k0, lds + tid * 8);                       // A tiles 0..3
    stage16(gA + 64 * D_ + k0, lds + 2048 + tid * 8);      // A tiles 4..7
    stage16(gB + k0, lds + 4096 + tid * 8);                // B tiles 0..3
    stage16(gB + 64 * D_ + k0, lds + 6144 + tid * 8);      // B tiles 4..7
    __syncthreads();
    bf8 aF[4], bF[4];
#pragma unroll
    for (int mi = 0; mi < 4; ++mi)
      aF[mi] = ldb(lds + (wr * 4 + mi) * 512 + lane * 8);
#pragma unroll
    for (int ni = 0; ni < 4; ++ni)
      bF[ni] = ldb(lds + 4096 + (wc * 4 + ni) * 512 + lane * 8);
#pragma unroll
    for (int mi = 0; mi < 4; ++mi)
#pragma unroll
      for (int ni = 0; ni < 4; ++ni)
        acc[mi][ni] = MFMA(aF[mi], bF[ni], acc[mi][ni]);
    __syncthreads();
  }
#pragma unroll
  for (int mi = 0; mi < 4; ++mi)
#pragma unroll
    for (int r = 0; r < 4; ++r) {
      long row = m0 + wr * 64 + mi * 16 + quad * 4 + r;
#pragma unroll
      for (int ni = 0; ni < 4; ++ni)
        C[row * D_ + n0 + wc * 64 + ni * 16 + l15] = f2bf_bits(acc[mi][ni][r] * scale);
    }
}

// ---- V projection split-K: partial[kc][row][64] f32, kc chunk = 256 ----
// grid (64 rowgroups of 64, 4 kc), block 256
__global__ __launch_bounds__(256) void k_pv(
    const float* __restrict__ v, const unsigned short* __restrict__ wvt,
    float* __restrict__ pv) {
  const int tid = threadIdx.x, wave = tid >> 6, lane = tid & 63;
  const int l15 = lane & 15, quad = lane >> 4;
  const int rg = blockIdx.x, kc = blockIdx.y;
  const int row0 = rg * 64 + wave * 16;
  const float* arow = v + (long)(row0 + l15) * D_ + kc * 256 + quad * 8;
  const unsigned short* wbase = wvt + kc * 256 + quad * 8;
  f4 acc[4];
  for (int i = 0; i < 4; ++i) acc[i] = f4{0.f, 0.f, 0.f, 0.f};
  for (int k0 = 0; k0 < 256; k0 += 32) {
    f4 alo = *reinterpret_cast<const f4*>(arow + k0);
    f4 ahi = *reinterpret_cast<const f4*>(arow + k0 + 4);
    bf8 a = pack_bf8(alo, ahi);
#pragma unroll
    for (int i = 0; i < 4; ++i) {
      bf8 bf = ldb(wbase + (long)(i * 16 + l15) * D_ + k0);
      acc[i] = MFMA(a, bf, acc[i]);
    }
  }
#pragma unroll
  for (int i = 0; i < 4; ++i)
#pragma unroll
    for (int r = 0; r < 4; ++r)
      pv[((long)kc * 4096 + row0 + quad * 4 + r) * 64 + i * 16 + l15] = acc[i][r];
}

// reduce 4 k-partials -> vst[b][dk][t] bf16 (writes coalesced over t)
__global__ void k_vred(const float* __restrict__ pv, unsigned short* __restrict__ vst) {
  int e = blockIdx.x * 256 + threadIdx.x;      // e = (b*64+dk)*2048 + t
  int t = e & 2047, dk = (e >> 11) & 63, b = e >> 17;
  long row = (long)b * S_ + t;
  float s = pv[row * 64 + dk] + pv[(4096 + row) * 64 + dk] +
            pv[(8192 + row) * 64 + dk] + pv[(12288 + row) * 64 + dk];
  vst[e] = f2bf_bits(s);
}

// ---- pass 1: recip[b,h,s] = 1/(H * sum_t exp2(qs.ks)) ----
// 1D grid 512, block 512 (8 waves); XCD-swizzled decode (r8). Q-frags hoisted.
// r11: 3-buffer rotation + counted vmcnt -- stage tile it+2 while computing it;
// end-of-iter wait vmcnt(2) (allow tile it+2's 2 loads in flight), never 0 in-loop.
__global__ __launch_bounds__(512) void k_denom(
    const unsigned short* __restrict__ qsb, const unsigned short* __restrict__ ksb,
    float* __restrict__ recip) {
  __shared__ unsigned short lds[24576];         // 3 x (128 t-rows x 64 dk), fragment-major
  const int tid = threadIdx.x, wave = tid >> 6, lane = tid & 63;
  const int l15 = lane & 15, quad = lane >> 4;
  const int n = blockIdx.x, xcd = n & 7, slot = n >> 3;
  const int b = xcd >> 2;
  const int h = ((xcd & 3) << 2) | (slot & 3);
  const int stile = slot >> 2;
  const int s0 = stile * 128 + wave * 16;

  const unsigned short* qrow = qsb + ((long)(b * S_) + s0 + l15) * D_ + h * 64 + quad * 8;
  bf8 a0 = ldb(qrow);
  bf8 a1 = ldb(qrow + 32);

  // staging decode: stt=(tid>>6)&7
  const int sl15 = tid & 15, squad = (tid >> 4) & 3, stt = (tid >> 6) & 7;
  const unsigned short* g0 =
      ksb + ((long)(b * S_) + stt * 16 + sl15) * D_ + h * 64 + squad * 8;

  // prologue: stage tiles 0,1 into buf0,buf1; wait only for tile 0 (vmcnt(2))
  stage16(g0, lds + tid * 8);
  stage16(g0 + 32, lds + 4096 + tid * 8);
  stage16(g0 + 128 * D_, lds + 8192 + tid * 8);
  stage16(g0 + 128 * D_ + 32, lds + 12288 + tid * 8);
  asm volatile("s_waitcnt vmcnt(2)" ::: "memory");
  __builtin_amdgcn_s_barrier();
  int rd = 0;

  f4 sum = f4{0.f, 0.f, 0.f, 0.f};
  for (int it = 0; it < 16; ++it) {
    if (it + 2 < 16) {
      const unsigned short* gn = g0 + (long)(it + 2) * 128 * D_;
      int wr = rd + 2; if (wr >= 3) wr -= 3;
      unsigned short* nb = lds + wr * 8192;
      stage16(gn, nb + tid * 8);
      stage16(gn + 32, nb + 4096 + tid * 8);
    }
    const unsigned short* base = lds + rd * 8192;
    __builtin_amdgcn_s_setprio(1);
#pragma unroll
    for (int tt = 0; tt < 8; ++tt) {
      bf8 b0 = ldb(base + tt * 512 + lane * 8);
      bf8 b1 = ldb(base + 4096 + tt * 512 + lane * 8);
      f4 d = f4{0.f, 0.f, 0.f, 0.f};
      d = MFMA(a0, b0, d);
      d = MFMA(a1, b1, d);
#pragma unroll
      for (int r = 0; r < 4; ++r) sum[r] += __builtin_amdgcn_exp2f(d[r]);
    }
    __builtin_amdgcn_s_setprio(0);
    if (it + 1 < 16) {
      if (it + 2 < 16)
        asm volatile("s_waitcnt vmcnt(2)" ::: "memory");   // tile it+1 landed; it+2 in flight
      else
        asm volatile("s_waitcnt vmcnt(0)" ::: "memory");   // drain for final tile
      __builtin_amdgcn_s_barrier();
      rd = (rd + 1 == 3) ? 0 : rd + 1;
    }
  }
#pragma unroll
  for (int m = 1; m < 16; m <<= 1) {
#pragma unroll
    for (int r = 0; r < 4; ++r) sum[r] += __shfl_xor(sum[r], m, 64);
  }
  if (l15 == 0) {
    float* rp = recip + (long)(b * H_ + h) * S_ + s0 + quad * 4;
#pragma unroll
    for (int r = 0; r < 4; ++r) rp[r] = 1.0f / (16.0f * sum[r]);
  }
}

// ---- pass 2: attn_mean[b,s,t] = sum_h recip[b,h,s]*exp2(score) ----
// 1D grid 512, block 512 (8 waves); XCD-swizzled decode (r8) + Q-frag register prefetch
// (r9). r11: 3-buffer rotation + counted vmcnt -- stage head h+2 while computing h;
// end-of-iter wait vmcnt(5) (= regs(h+1)[3] + stages(h+2)[2] allowed in flight; only
// stages(h+1) must have landed). Staging gets 2 full compute phases to cover its latency.
__global__ __launch_bounds__(512) void k_attn(
    const unsigned short* __restrict__ qsb, const unsigned short* __restrict__ ksb,
    const float* __restrict__ recip, float* __restrict__ am) {
  __shared__ unsigned short lds[24576];         // 3 x (128 t-rows x 64 dk)
  const int tid = threadIdx.x, wave = tid >> 6, lane = tid & 63;
  const int l15 = lane & 15, quad = lane >> 4;
  const int n = blockIdx.x, xcd = n & 7, slot = n >> 3;
  const int b = xcd >> 2;
  const int tchunk = ((xcd & 1) << 3) | (slot & 7);
  const int stile = (((xcd >> 1) & 1) << 3) | (slot >> 3);
  const int s0 = stile * 128 + wave * 16;
  const int t0c = tchunk * 128;

  f4 acc[8];
#pragma unroll
  for (int tt = 0; tt < 8; ++tt) acc[tt] = f4{0.f, 0.f, 0.f, 0.f};

  const unsigned short* qbase = qsb + ((long)(b * S_) + s0 + l15) * D_ + quad * 8;
  // staging decode: stt=(tid>>6)&7
  const int sl15 = tid & 15, squad = (tid >> 4) & 3, stt = (tid >> 6) & 7;
  const unsigned short* g0 =
      ksb + ((long)(b * S_) + t0c + stt * 16 + sl15) * D_ + squad * 8;
  const float* rbase = recip + (long)(b * H_) * S_ + s0 + quad * 4;

  // prologue: regs(h=0) FIRST (oldest), then stage heads 0,1; wait vmcnt(2)
  // (regs + head-0 staging landed; head-1 staging still in flight).
  bf8 a0 = ldb(qbase);
  bf8 a1 = ldb(qbase + 32);
  f4 rp = *reinterpret_cast<const f4*>(rbase);
  __builtin_amdgcn_sched_barrier(0);
  stage16(g0, lds + tid * 8);
  stage16(g0 + 32, lds + 4096 + tid * 8);
  stage16(g0 + 64, lds + 8192 + tid * 8);
  stage16(g0 + 96, lds + 12288 + tid * 8);
  asm volatile("s_waitcnt vmcnt(2)" ::: "memory");
  __builtin_amdgcn_s_barrier();
  int rd = 0;

  for (int h = 0; h < H_; ++h) {
    bf8 a0n, a1n;
    f4 rpn;
    if (h + 1 < H_) {
      // register prefetch for head h+1, issued BEFORE the staging (in-order vmcnt)
      a0n = ldb(qbase + (h + 1) * 64);
      a1n = ldb(qbase + (h + 1) * 64 + 32);
      rpn = *reinterpret_cast<const f4*>(rbase + (long)(h + 1) * S_);
      __builtin_amdgcn_sched_barrier(0);        // pin: reg loads above, staging below
    }
    if (h + 2 < H_) {
      const unsigned short* gn = g0 + (h + 2) * 64;
      int wr = rd + 2; if (wr >= 3) wr -= 3;
      unsigned short* nb = lds + wr * 8192;
      stage16(gn, nb + tid * 8);
      stage16(gn + 32, nb + 4096 + tid * 8);
    }
    const unsigned short* base = lds + rd * 8192;
    __builtin_amdgcn_s_setprio(1);
#pragma unroll
    for (int tt = 0; tt < 8; ++tt) {
      bf8 b0 = ldb(base + tt * 512 + lane * 8);
      bf8 b1 = ldb(base + 4096 + tt * 512 + lane * 8);
      f4 d = f4{0.f, 0.f, 0.f, 0.f};
      d = MFMA(a0, b0, d);
      d = MFMA(a1, b1, d);
#pragma unroll
      for (int r = 0; r < 4; ++r) acc[tt][r] += rp[r] * __builtin_amdgcn_exp2f(d[r]);
    }
    __builtin_amdgcn_s_setprio(0);
    if (h + 1 < H_) {
      if (h + 2 < H_)
        asm volatile("s_waitcnt vmcnt(5)" ::: "memory");   // stages(h+1) landed
      else
        asm volatile("s_waitcnt vmcnt(3)" ::: "memory");   // only regs(h+1) in flight
      __builtin_amdgcn_s_barrier();
      rd = (rd + 1 == 3) ? 0 : rd + 1;
      a0 = a0n;
      a1 = a1n;
      rp = rpn;
    }
  }
  float* obase = am + ((long)b * S_ + s0 + quad * 4) * S_ + t0c + l15;
#pragma unroll
  for (int tt = 0; tt < 8; ++tt)
#pragma unroll
    for (int r = 0; r < 4; ++r) obase[(long)r * S_ + tt * 16] = acc[tt][r];
}

// ---- head split-K: ph[kc][row][64] f32 = am-chunk @ vs-chunk, kc chunk = 512 t ----
// grid (64 rowgroups, 4 kc), block 256
__global__ __launch_bounds__(256) void k_hpart(
    const float* __restrict__ am, const unsigned short* __restrict__ vst,
    float* __restrict__ ph) {
  const int tid = threadIdx.x, wave = tid >> 6, lane = tid & 63;
  const int l15 = lane & 15, quad = lane >> 4;
  const int rg = blockIdx.x, kc = blockIdx.y;
  const int row0 = rg * 64 + wave * 16;
  const int b = row0 >> 11;
  const float* arow = am + (long)(row0 + l15) * S_ + kc * 512 + quad * 8;
  const unsigned short* vb = vst + (long)b * DK_ * S_ + kc * 512 + quad * 8;
  f4 acc[4];
  for (int i = 0; i < 4; ++i) acc[i] = f4{0.f, 0.f, 0.f, 0.f};
  for (int t0 = 0; t0 < 512; t0 += 32) {
    f4 alo = *reinterpret_cast<const f4*>(arow + t0);
    f4 ahi = *reinterpret_cast<const f4*>(arow + t0 + 4);
    bf8 a = pack_bf8(alo, ahi);
#pragma unroll
    for (int i = 0; i < 4; ++i) {
      bf8 bf = ldb(vb + (long)(i * 16 + l15) * S_ + t0);
      acc[i] = MFMA(a, bf, acc[i]);
    }
  }
#pragma unroll
  for (int i = 0; i < 4; ++i)
#pragma unroll
    for (int r = 0; r < 4; ++r)
      ph[((long)kc * 4096 + row0 + quad * 4 + r) * 64 + i * 16 + l15] = acc[i][r];
}

// reduce -> headb bf16 [row][64] (fully coalesced)
__global__ void k_hred(const float* __restrict__ ph, unsigned short* __restrict__ headb) {
  int e = blockIdx.x * 256 + threadIdx.x;      // e = row*64 + dk
  float s = ph[e] + ph[e + 4096 * 64] + ph[e + 2 * 4096 * 64] + ph[e + 3 * 4096 * 64];
  headb[e] = f2bf_bits(s);
}

// ---- out = head @ Wo ----
// grid (8 d-chunks of 128, 32 s-tiles of 64, B), block 256
__global__ __launch_bounds__(256) void k_out(
    const unsigned short* __restrict__ head, const unsigned short* __restrict__ wot,
    float* __restrict__ out) {
  const int tid = threadIdx.x, wave = tid >> 6, lane = tid & 63;
  const int l15 = lane & 15, quad = lane >> 4;
  const int dchunk = blockIdx.x, stile = blockIdx.y, b = blockIdx.z;
  const int s0 = stile * 64 + wave * 16;
  const int n0 = dchunk * 128;
  const unsigned short* hrow = head + ((long)b * S_ + s0 + l15) * DK_ + quad * 8;
  bf8 a0 = ldb(hrow);
  bf8 a1 = ldb(hrow + 32);
  const unsigned short* wb = wot + quad * 8;
  float* obase = out + ((long)b * S_ + s0 + quad * 4) * D_ + n0 + l15;
#pragma unroll
  for (int i = 0; i < 8; ++i) {
    const unsigned short* wp = wb + (long)(n0 + i * 16 + l15) * DK_;
    bf8 b0 = ldb(wp);
    bf8 b1 = ldb(wp + 32);
    f4 d = f4{0.f, 0.f, 0.f, 0.f};
    d = MFMA(a0, b0, d);
    d = MFMA(a1, b1, d);
#pragma unroll
    for (int r = 0; r < 4; ++r) obase[(long)r * D_ + i * 16] = d[r];
  }
}

extern "C" void kernel_launch(void* const* d_in, const int* in_sizes, int n_in,
                              void* d_out, int out_size, void* d_ws, size_t ws_size,
                              hipStream_t stream) {
  const float* q  = (const float*)d_in[0];
  const float* k  = (const float*)d_in[1];
  const float* v  = (const float*)d_in[2];
  const float* Wq = (const float*)d_in[3];
  const float* Wk = (const float*)d_in[4];
  const float* Wv = (const float*)d_in[5];
  const float* Wo = (const float*)d_in[6];

  float* out = (float*)d_out;                       // [B,S,D] = 4,194,304 f32
  float* am  = out + (long)B_ * S_ * D_;            // [B,S,S] = 8,388,608 f32

  // workspace (~22.5 MB)
  unsigned short* qsb  = (unsigned short*)d_ws;     // [4096][1024]
  unsigned short* ksb  = qsb + 4194304;
  unsigned short* wqt  = ksb + 4194304;             // [1024][1024]
  unsigned short* wkt  = wqt + 1048576;
  unsigned short* wvt  = wkt + 1048576;             // [64][1024]
  unsigned short* wot  = wvt + 65536;               // [1024][64]
  unsigned short* vst  = wot + 65536;               // [B][64][S]
  unsigned short* headb= vst + 262144;              // [4096][64]
  float* recip = (float*)(headb + 262144);          // [B*H*S]

  // bf16 q,k copies live in the am region of d_out (dead before k_attn writes am)
  unsigned short* qb = (unsigned short*)am;         // [4096][1024]
  unsigned short* kb = qb + 4194304;
  // split-K f32 partials [4][4096][64] live in the out region (dead until k_out)
  float* part = out;

  k_prep<<<4384, 256, 0, stream>>>(q, k, Wq, Wk, Wv, Wo, qb, kb, wqt, wkt, wvt, wot);
  k_gemm_qk<<<dim3(32, 8, 2), 256, 0, stream>>>(qb, kb, wqt, wkt, qsb, ksb);
  k_pv<<<dim3(64, 4), 256, 0, stream>>>(v, wvt, part);
  k_vred<<<1024, 256, 0, stream>>>(part, vst);
  k_denom<<<512, 512, 0, stream>>>(qsb, ksb, recip);
  k_attn<<<512, 512, 0, stream>>>(qsb, ksb, recip, am);
  k_hpart<<<dim3(64, 4), 256, 0, stream>>>(am, vst, part);
  k_hred<<<1024, 256, 0, stream>>>(part, headb);
  k_out<<<dim3(8, 32, 2), 256, 0, stream>>>(headb, wot, out);
}

// Round 13
// 237.229 us; speedup vs baseline: 1.1921x; 1.0192x over previous
//
#include <hip/hip_runtime.h>

// B=2, S=2048, D=1024, H=16, DK=64
// out = attn_mean @ vs @ Wo  (Wv shared across heads => mean_h(attn_h @ vs) = attn_mean @ vs)
// attn_mean[b,s,t] = (1/H) sum_h exp(score)/denom  -- no max-subtraction (scores bounded ~|2.5|)
// qs/ks layout: [b*S+s][h*64+dk]  (concatenated-head GEMM output)
// All LDS tiles are FRAGMENT-MAJOR: 16B-unit index = tile*64 + quad*16 + l15
//   -> reader addr = tilebase + lane*16B, conflict-free for ds_read_b128.
// r13 = r12 resubmit (container flake; kernel audited: vmcnt invariant, WAR-across-
// barrier safety, swizzle bijectivity all check out).
// r12 = r9 config (best, 240.0us) + k_gemm_qk REWORK: it was the new #1 (46.5us = 370 TF
// vs the same structure's verified 874 TF). At 2 blocks/CU its 32 per-K-step vmcnt(0)
// barrier drains are unhidden (m114: cross-block overlap is the hider; m97 had 3/CU).
// Fix: 3-buffer LDS rotation + counted vmcnt(4) (stage k+2 while computing k; never
// drain to 0 in-loop) + XCD swizzle (per-XCD working set 2MB A-panel + 2MB B = 4MB = L2).
#define B_ 2
#define S_ 2048
#define D_ 1024
#define H_ 16
#define DK_ 64

typedef __bf16 bf8 __attribute__((ext_vector_type(8)));
typedef float f4 __attribute__((ext_vector_type(4)));
typedef unsigned short u16x8 __attribute__((ext_vector_type(8)));

__device__ __forceinline__ unsigned short f2bf_bits(float f) {
  unsigned int u = __float_as_uint(f);
  return (unsigned short)((u + 0x7fffu + ((u >> 16) & 1u)) >> 16);
}

__device__ __forceinline__ bf8 pack_bf8(f4 lo, f4 hi) {
  u16x8 u;
  u[0] = f2bf_bits(lo[0]); u[1] = f2bf_bits(lo[1]);
  u[2] = f2bf_bits(lo[2]); u[3] = f2bf_bits(lo[3]);
  u[4] = f2bf_bits(hi[0]); u[5] = f2bf_bits(hi[1]);
  u[6] = f2bf_bits(hi[2]); u[7] = f2bf_bits(hi[3]);
  union { u16x8 u; bf8 b; } x; x.u = u; return x.b;
}

__device__ __forceinline__ bf8 ldb(const unsigned short* p) {
  return *reinterpret_cast<const bf8*>(p);
}

__device__ __forceinline__ void stage16(const void* g, void* l) {
  __builtin_amdgcn_global_load_lds(
      (const __attribute__((address_space(1))) void*)g,
      (__attribute__((address_space(3))) void*)l, 16, 0, 0);
}

#define MFMA(a, b, c) __builtin_amdgcn_mfma_f32_16x16x32_bf16((a), (b), (c), 0, 0, 0)

// ---- merged prep: cast q,k -> bf16 rows; LDS-tiled transpose-cast weights ----
// blocks 0..4095: cast q/k | 4096..4351: wq/wk 64x64 tiles | 4352..4367: wv | 4368..4383: wo
__global__ void k_prep(const float* __restrict__ q, const float* __restrict__ k,
                       const float* __restrict__ wq, const float* __restrict__ wk,
                       const float* __restrict__ wv, const float* __restrict__ wo,
                       unsigned short* __restrict__ qb, unsigned short* __restrict__ kb,
                       unsigned short* __restrict__ wqt, unsigned short* __restrict__ wkt,
                       unsigned short* __restrict__ wvt, unsigned short* __restrict__ wot) {
  __shared__ float tl[64 * 65];
  int bid = blockIdx.x, tid = threadIdx.x;
  const int rr = tid >> 6, cc = tid & 63;
  if (bid < 4096) {
    int which = bid >> 11;
    long i = ((long)(bid & 2047) * 256 + tid) * 8;
    const float* src = which ? k : q;
    unsigned short* dst = which ? kb : qb;
    f4 lo = *reinterpret_cast<const f4*>(src + i);
    f4 hi = *reinterpret_cast<const f4*>(src + i + 4);
    *reinterpret_cast<bf8*>(dst + i) = pack_bf8(lo, hi);
  } else if (bid < 4352) {
    // Wq/Wk [h][d][n=dk] -> [h][n][d], 64x64 f32 tile via LDS (coalesced both ways)
    int blk = bid - 4096;
    int h = blk >> 4, d0 = (blk & 15) * 64;
    for (int m = 0; m < 2; ++m) {
      const float* src = m ? wk : wq;
      unsigned short* dst = m ? wkt : wqt;
      if (m) __syncthreads();
#pragma unroll
      for (int it = 0; it < 16; ++it) {
        int d = it * 4 + rr;
        tl[cc * 65 + d] = src[(long)h * 65536 + (d0 + d) * 64 + cc];
      }
      __syncthreads();
#pragma unroll
      for (int it = 0; it < 16; ++it) {
        int n = it * 4 + rr;
        dst[(long)h * 65536 + n * 1024 + d0 + cc] = f2bf_bits(tl[n * 65 + cc]);
      }
    }
  } else if (bid < 4368) {
    // Wv [d][n=dk] -> [n][d]
    int d0 = (bid - 4352) * 64;
#pragma unroll
    for (int it = 0; it < 16; ++it) {
      int d = it * 4 + rr;
      tl[cc * 65 + d] = wv[(long)(d0 + d) * 64 + cc];
    }
    __syncthreads();
#pragma unroll
    for (int it = 0; it < 16; ++it) {
      int n = it * 4 + rr;
      wvt[(long)n * 1024 + d0 + cc] = f2bf_bits(tl[n * 65 + cc]);
    }
  } else {
    // Wo [kk][dd] -> [dd][kk]
    int d0 = (bid - 4368) * 64;
#pragma unroll
    for (int it = 0; it < 16; ++it) {
      int kk = it * 4 + rr;
      tl[cc * 65 + kk] = wo[(long)kk * 1024 + d0 + cc];   // tl[ddl][kk]
    }
    __syncthreads();
#pragma unroll
    for (int it = 0; it < 16; ++it) {
      int ddl = it * 4 + rr;
      wot[(long)(d0 + ddl) * 64 + cc] = f2bf_bits(tl[ddl * 65 + cc]);
    }
  }
}

// ---- GEMM: C[4096][1024] = X @ W^T, 128x128 tile, BK=32 (m97 geometry) ----
// r12: 1D grid 512, XCD-swizzled (xcd=n&7 -> which = xcd>>2, m-group = xcd&3; per-XCD
// working set = 8 m-tiles x 256KB A + full 2MB B = 4MB = one L2). 3-buffer LDS rotation
// with counted vmcnt: stage tile k+2 while computing k; end-of-iter wait vmcnt(4)
// (tile k+1 landed, k+2's 4 stages in flight) -- never 0 in-loop.
__global__ __launch_bounds__(256) void k_gemm_qk(
    const unsigned short* __restrict__ qb, const unsigned short* __restrict__ kb,
    const unsigned short* __restrict__ wqt, const unsigned short* __restrict__ wkt,
    unsigned short* __restrict__ qsb, unsigned short* __restrict__ ksb) {
  __shared__ unsigned short lds[24576];         // 3 x (A 8 tiles @0, B 8 tiles @4096)
  const int tid = threadIdx.x, wave = tid >> 6, lane = tid & 63;
  const int l15 = lane & 15, quad = lane >> 4;
  const int n = blockIdx.x, xcd = n & 7, slot = n >> 3;   // slot 0..63
  const int which = xcd >> 2;                              // 0..1
  const int m0 = (((xcd & 3) << 3) | (slot & 7)) * 128;    // 32 m-tiles
  const int n0 = (slot >> 3) * 128;                        // 8 n-tiles
  const unsigned short* A = which ? kb : qb;
  const unsigned short* W = which ? wkt : wqt;
  unsigned short* C = which ? ksb : qsb;
  const float scale = which ? 1.0f : 0.18033688011112042f;  // log2(e)/8 folded into qs
  const int wr = wave >> 1, wc = wave & 1;

  f4 acc[4][4];
#pragma unroll
  for (int i = 0; i < 4; ++i)
#pragma unroll
    for (int j = 0; j < 4; ++j) acc[i][j] = f4{0.f, 0.f, 0.f, 0.f};

  // staging decode: u = i*256+tid; tile=u>>6 (st + i*4), quad=(u>>4)&3, l15=u&15
  const int sl15 = tid & 15, squad = (tid >> 4) & 3, st = tid >> 6;
  const unsigned short* gA = A + (long)(m0 + st * 16 + sl15) * D_ + squad * 8;
  const unsigned short* gB = W + (long)(n0 + st * 16 + sl15) * D_ + squad * 8;

  // prologue: stage k-tiles 0 (buf0) and 1 (buf1); wait only for tile 0
  stage16(gA, lds + tid * 8);
  stage16(gA + 64 * D_, lds + 2048 + tid * 8);
  stage16(gB, lds + 4096 + tid * 8);
  stage16(gB + 64 * D_, lds + 6144 + tid * 8);
  stage16(gA + 32, lds + 8192 + tid * 8);
  stage16(gA + 64 * D_ + 32, lds + 10240 + tid * 8);
  stage16(gB + 32, lds + 12288 + tid * 8);
  stage16(gB + 64 * D_ + 32, lds + 14336 + tid * 8);
  asm volatile("s_waitcnt vmcnt(4)" ::: "memory");
  __builtin_amdgcn_s_barrier();
  int rd = 0;

  for (int it = 0; it < 32; ++it) {
    if (it + 2 < 32) {
      const int k2 = (it + 2) * 32;
      int wb = rd + 2; if (wb >= 3) wb -= 3;
      unsigned short* nb = lds + wb * 8192;
      stage16(gA + k2, nb + tid * 8);
      stage16(gA + 64 * D_ + k2, nb + 2048 + tid * 8);
      stage16(gB + k2, nb + 4096 + tid * 8);
      stage16(gB + 64 * D_ + k2, nb + 6144 + tid * 8);
    }
    const unsigned short* base = lds + rd * 8192;
    __builtin_amdgcn_s_setprio(1);
    bf8 aF[4], bF[4];
#pragma unroll
    for (int mi = 0; mi < 4; ++mi)
      aF[mi] = ldb(base + (wr * 4 + mi) * 512 + lane * 8);
#pragma unroll
    for (int ni = 0; ni < 4; ++ni)
      bF[ni] = ldb(base + 4096 + (wc * 4 + ni) * 512 + lane * 8);
#pragma unroll
    for (int mi = 0; mi < 4; ++mi)
#pragma unroll
      for (int ni = 0; ni < 4; ++ni)
        acc[mi][ni] = MFMA(aF[mi], bF[ni], acc[mi][ni]);
    __builtin_amdgcn_s_setprio(0);
    if (it + 1 < 32) {
      if (it + 2 < 32)
        asm volatile("s_waitcnt vmcnt(4)" ::: "memory");   // tile it+1 landed; it+2 in flight
      else
        asm volatile("s_waitcnt vmcnt(0)" ::: "memory");   // drain for final tile
      __builtin_amdgcn_s_barrier();
      rd = (rd + 1 == 3) ? 0 : rd + 1;
    }
  }
#pragma unroll
  for (int mi = 0; mi < 4; ++mi)
#pragma unroll
    for (int r = 0; r < 4; ++r) {
      long row = m0 + wr * 64 + mi * 16 + quad * 4 + r;
#pragma unroll
      for (int ni = 0; ni < 4; ++ni)
        C[row * D_ + n0 + wc * 64 + ni * 16 + l15] = f2bf_bits(acc[mi][ni][r] * scale);
    }
}

// ---- V projection split-K: partial[kc][row][64] f32, kc chunk = 256 ----
// grid (64 rowgroups of 64, 4 kc), block 256
__global__ __launch_bounds__(256) void k_pv(
    const float* __restrict__ v, const unsigned short* __restrict__ wvt,
    float* __restrict__ pv) {
  const int tid = threadIdx.x, wave = tid >> 6, lane = tid & 63;
  const int l15 = lane & 15, quad = lane >> 4;
  const int rg = blockIdx.x, kc = blockIdx.y;
  const int row0 = rg * 64 + wave * 16;
  const float* arow = v + (long)(row0 + l15) * D_ + kc * 256 + quad * 8;
  const unsigned short* wbase = wvt + kc * 256 + quad * 8;
  f4 acc[4];
  for (int i = 0; i < 4; ++i) acc[i] = f4{0.f, 0.f, 0.f, 0.f};
  for (int k0 = 0; k0 < 256; k0 += 32) {
    f4 alo = *reinterpret_cast<const f4*>(arow + k0);
    f4 ahi = *reinterpret_cast<const f4*>(arow + k0 + 4);
    bf8 a = pack_bf8(alo, ahi);
#pragma unroll
    for (int i = 0; i < 4; ++i) {
      bf8 bf = ldb(wbase + (long)(i * 16 + l15) * D_ + k0);
      acc[i] = MFMA(a, bf, acc[i]);
    }
  }
#pragma unroll
  for (int i = 0; i < 4; ++i)
#pragma unroll
    for (int r = 0; r < 4; ++r)
      pv[((long)kc * 4096 + row0 + quad * 4 + r) * 64 + i * 16 + l15] = acc[i][r];
}

// reduce 4 k-partials -> vst[b][dk][t] bf16 (writes coalesced over t)
__global__ void k_vred(const float* __restrict__ pv, unsigned short* __restrict__ vst) {
  int e = blockIdx.x * 256 + threadIdx.x;      // e = (b*64+dk)*2048 + t
  int t = e & 2047, dk = (e >> 11) & 63, b = e >> 17;
  long row = (long)b * S_ + t;
  float s = pv[row * 64 + dk] + pv[(4096 + row) * 64 + dk] +
            pv[(8192 + row) * 64 + dk] + pv[(12288 + row) * 64 + dk];
  vst[e] = f2bf_bits(s);
}

// ---- pass 1: recip[b,h,s] = 1/(H * sum_t exp2(qs.ks)) ----
// 1D grid 512, block 512 (8 waves); XCD-swizzled decode (r8). Q-frags hoisted.
// r9 structure (best measured): 2-phase dbuf, vmcnt(0)+s_barrier per tile, setprio.
__global__ __launch_bounds__(512) void k_denom(
    const unsigned short* __restrict__ qsb, const unsigned short* __restrict__ ksb,
    float* __restrict__ recip) {
  __shared__ unsigned short lds[16384];         // 2 x (128 t-rows x 64 dk), fragment-major
  const int tid = threadIdx.x, wave = tid >> 6, lane = tid & 63;
  const int l15 = lane & 15, quad = lane >> 4;
  const int n = blockIdx.x, xcd = n & 7, slot = n >> 3;
  const int b = xcd >> 2;
  const int h = ((xcd & 3) << 2) | (slot & 3);
  const int stile = slot >> 2;
  const int s0 = stile * 128 + wave * 16;

  const unsigned short* qrow = qsb + ((long)(b * S_) + s0 + l15) * D_ + h * 64 + quad * 8;
  bf8 a0 = ldb(qrow);
  bf8 a1 = ldb(qrow + 32);

  // staging decode for u = tid (sh2=0) and u = tid+512 (sh2=1): stt=(tid>>6)&7
  const int sl15 = tid & 15, squad = (tid >> 4) & 3, stt = (tid >> 6) & 7;
  const unsigned short* g0 =
      ksb + ((long)(b * S_) + stt * 16 + sl15) * D_ + h * 64 + squad * 8;

  // prologue: stage tile 0 into buf0
  stage16(g0, lds + tid * 8);
  stage16(g0 + 32, lds + 4096 + tid * 8);
  asm volatile("s_waitcnt vmcnt(0)" ::: "memory");
  __builtin_amdgcn_s_barrier();
  int cur = 0;

  f4 sum = f4{0.f, 0.f, 0.f, 0.f};
  for (int it = 0; it < 16; ++it) {
    if (it + 1 < 16) {
      const unsigned short* gn = g0 + (long)(it + 1) * 128 * D_;
      unsigned short* nb = lds + (cur ^ 1) * 8192;
      stage16(gn, nb + tid * 8);
      stage16(gn + 32, nb + 4096 + tid * 8);
    }
    const unsigned short* base = lds + cur * 8192;
    __builtin_amdgcn_s_setprio(1);
#pragma unroll
    for (int tt = 0; tt < 8; ++tt) {
      bf8 b0 = ldb(base + tt * 512 + lane * 8);
      bf8 b1 = ldb(base + 4096 + tt * 512 + lane * 8);
      f4 d = f4{0.f, 0.f, 0.f, 0.f};
      d = MFMA(a0, b0, d);
      d = MFMA(a1, b1, d);
#pragma unroll
      for (int r = 0; r < 4; ++r) sum[r] += __builtin_amdgcn_exp2f(d[r]);
    }
    __builtin_amdgcn_s_setprio(0);
    if (it + 1 < 16) {
      asm volatile("s_waitcnt vmcnt(0)" ::: "memory");
      __builtin_amdgcn_s_barrier();
      cur ^= 1;
    }
  }
#pragma unroll
  for (int m = 1; m < 16; m <<= 1) {
#pragma unroll
    for (int r = 0; r < 4; ++r) sum[r] += __shfl_xor(sum[r], m, 64);
  }
  if (l15 == 0) {
    float* rp = recip + (long)(b * H_ + h) * S_ + s0 + quad * 4;
#pragma unroll
    for (int r = 0; r < 4; ++r) rp[r] = 1.0f / (16.0f * sum[r]);
  }
}

// ---- pass 2: attn_mean[b,s,t] = sum_h recip[b,h,s]*exp2(score) ----
// 1D grid 512, block 512 (8 waves); XCD-swizzled decode (r8) + Q-frag register prefetch
// (r9, best measured): load h+1's a0n/a1n/rpn BEFORE its stage16 (sched_barrier pins
// order), compute consumes preloaded regs, rotate after barrier.
__global__ __launch_bounds__(512) void k_attn(
    const unsigned short* __restrict__ qsb, const unsigned short* __restrict__ ksb,
    const float* __restrict__ recip, float* __restrict__ am) {
  __shared__ unsigned short lds[16384];         // 2 x (128 t-rows x 64 dk) per head
  const int tid = threadIdx.x, wave = tid >> 6, lane = tid & 63;
  const int l15 = lane & 15, quad = lane >> 4;
  const int n = blockIdx.x, xcd = n & 7, slot = n >> 3;
  const int b = xcd >> 2;
  const int tchunk = ((xcd & 1) << 3) | (slot & 7);
  const int stile = (((xcd >> 1) & 1) << 3) | (slot >> 3);
  const int s0 = stile * 128 + wave * 16;
  const int t0c = tchunk * 128;

  f4 acc[8];
#pragma unroll
  for (int tt = 0; tt < 8; ++tt) acc[tt] = f4{0.f, 0.f, 0.f, 0.f};

  const unsigned short* qbase = qsb + ((long)(b * S_) + s0 + l15) * D_ + quad * 8;
  // staging decode for u = tid (sh2=0) and u = tid+512 (sh2=1): stt=(tid>>6)&7
  const int sl15 = tid & 15, squad = (tid >> 4) & 3, stt = (tid >> 6) & 7;
  const unsigned short* g0 =
      ksb + ((long)(b * S_) + t0c + stt * 16 + sl15) * D_ + squad * 8;
  const float* rbase = recip + (long)(b * H_) * S_ + s0 + quad * 4;

  // prologue: stage head 0 into buf0; load head 0's Q-frags + recip
  stage16(g0, lds + tid * 8);
  stage16(g0 + 32, lds + 4096 + tid * 8);
  bf8 a0 = ldb(qbase);
  bf8 a1 = ldb(qbase + 32);
  f4 rp = *reinterpret_cast<const f4*>(rbase);
  asm volatile("s_waitcnt vmcnt(0)" ::: "memory");
  __builtin_amdgcn_s_barrier();
  int cur = 0;

  for (int h = 0; h < H_; ++h) {
    bf8 a0n, a1n;
    f4 rpn;
    if (h + 1 < H_) {
      // register prefetch for head h+1 -- issued BEFORE the stage16s (in-order vmcnt)
      a0n = ldb(qbase + (h + 1) * 64);
      a1n = ldb(qbase + (h + 1) * 64 + 32);
      rpn = *reinterpret_cast<const f4*>(rbase + (long)(h + 1) * S_);
      __builtin_amdgcn_sched_barrier(0);        // pin: reg loads above, staging below
      const unsigned short* gn = g0 + (h + 1) * 64;
      unsigned short* nb = lds + (cur ^ 1) * 8192;
      stage16(gn, nb + tid * 8);
      stage16(gn + 32, nb + 4096 + tid * 8);
    }
    const unsigned short* base = lds + cur * 8192;
    __builtin_amdgcn_s_setprio(1);
#pragma unroll
    for (int tt = 0; tt < 8; ++tt) {
      bf8 b0 = ldb(base + tt * 512 + lane * 8);
      bf8 b1 = ldb(base + 4096 + tt * 512 + lane * 8);
      f4 d = f4{0.f, 0.f, 0.f, 0.f};
      d = MFMA(a0, b0, d);
      d = MFMA(a1, b1, d);
#pragma unroll
      for (int r = 0; r < 4; ++r) acc[tt][r] += rp[r] * __builtin_amdgcn_exp2f(d[r]);
    }
    __builtin_amdgcn_s_setprio(0);
    if (h + 1 < H_) {
      asm volatile("s_waitcnt vmcnt(0)" ::: "memory");
      __builtin_amdgcn_s_barrier();
      cur ^= 1;
      a0 = a0n;
      a1 = a1n;
      rp = rpn;
    }
  }
  float* obase = am + ((long)b * S_ + s0 + quad * 4) * S_ + t0c + l15;
#pragma unroll
  for (int tt = 0; tt < 8; ++tt)
#pragma unroll
    for (int r = 0; r < 4; ++r) obase[(long)r * S_ + tt * 16] = acc[tt][r];
}

// ---- head split-K: ph[kc][row][64] f32 = am-chunk @ vs-chunk, kc chunk = 512 t ----
// grid (64 rowgroups, 4 kc), block 256
__global__ __launch_bounds__(256) void k_hpart(
    const float* __restrict__ am, const unsigned short* __restrict__ vst,
    float* __restrict__ ph) {
  const int tid = threadIdx.x, wave = tid >> 6, lane = tid & 63;
  const int l15 = lane & 15, quad = lane >> 4;
  const int rg = blockIdx.x, kc = blockIdx.y;
  const int row0 = rg * 64 + wave * 16;
  const int b = row0 >> 11;
  const float* arow = am + (long)(row0 + l15) * S_ + kc * 512 + quad * 8;
  const unsigned short* vb = vst + (long)b * DK_ * S_ + kc * 512 + quad * 8;
  f4 acc[4];
  for (int i = 0; i < 4; ++i) acc[i] = f4{0.f, 0.f, 0.f, 0.f};
  for (int t0 = 0; t0 < 512; t0 += 32) {
    f4 alo = *reinterpret_cast<const f4*>(arow + t0);
    f4 ahi = *reinterpret_cast<const f4*>(arow + t0 + 4);
    bf8 a = pack_bf8(alo, ahi);
#pragma unroll
    for (int i = 0; i < 4; ++i) {
      bf8 bf = ldb(vb + (long)(i * 16 + l15) * S_ + t0);
      acc[i] = MFMA(a, bf, acc[i]);
    }
  }
#pragma unroll
  for (int i = 0; i < 4; ++i)
#pragma unroll
    for (int r = 0; r < 4; ++r)
      ph[((long)kc * 4096 + row0 + quad * 4 + r) * 64 + i * 16 + l15] = acc[i][r];
}

// reduce -> headb bf16 [row][64] (fully coalesced)
__global__ void k_hred(const float* __restrict__ ph, unsigned short* __restrict__ headb) {
  int e = blockIdx.x * 256 + threadIdx.x;      // e = row*64 + dk
  float s = ph[e] + ph[e + 4096 * 64] + ph[e + 2 * 4096 * 64] + ph[e + 3 * 4096 * 64];
  headb[e] = f2bf_bits(s);
}

// ---- out = head @ Wo ----
// grid (8 d-chunks of 128, 32 s-tiles of 64, B), block 256
__global__ __launch_bounds__(256) void k_out(
    const unsigned short* __restrict__ head, const unsigned short* __restrict__ wot,
    float* __restrict__ out) {
  const int tid = threadIdx.x, wave = tid >> 6, lane = tid & 63;
  const int l15 = lane & 15, quad = lane >> 4;
  const int dchunk = blockIdx.x, stile = blockIdx.y, b = blockIdx.z;
  const int s0 = stile * 64 + wave * 16;
  const int n0 = dchunk * 128;
  const unsigned short* hrow = head + ((long)b * S_ + s0 + l15) * DK_ + quad * 8;
  bf8 a0 = ldb(hrow);
  bf8 a1 = ldb(hrow + 32);
  const unsigned short* wb = wot + quad * 8;
  float* obase = out + ((long)b * S_ + s0 + quad * 4) * D_ + n0 + l15;
#pragma unroll
  for (int i = 0; i < 8; ++i) {
    const unsigned short* wp = wb + (long)(n0 + i * 16 + l15) * DK_;
    bf8 b0 = ldb(wp);
    bf8 b1 = ldb(wp + 32);
    f4 d = f4{0.f, 0.f, 0.f, 0.f};
    d = MFMA(a0, b0, d);
    d = MFMA(a1, b1, d);
#pragma unroll
    for (int r = 0; r < 4; ++r) obase[(long)r * D_ + i * 16] = d[r];
  }
}

extern "C" void kernel_launch(void* const* d_in, const int* in_sizes, int n_in,
                              void* d_out, int out_size, void* d_ws, size_t ws_size,
                              hipStream_t stream) {
  const float* q  = (const float*)d_in[0];
  const float* k  = (const float*)d_in[1];
  const float* v  = (const float*)d_in[2];
  const float* Wq = (const float*)d_in[3];
  const float* Wk = (const float*)d_in[4];
  const float* Wv = (const float*)d_in[5];
  const float* Wo = (const float*)d_in[6];

  float* out = (float*)d_out;                       // [B,S,D] = 4,194,304 f32
  float* am  = out + (long)B_ * S_ * D_;            // [B,S,S] = 8,388,608 f32

  // workspace (~22.5 MB)
  unsigned short* qsb  = (unsigned short*)d_ws;     // [4096][1024]
  unsigned short* ksb  = qsb + 4194304;
  unsigned short* wqt  = ksb + 4194304;             // [1024][1024]
  unsigned short* wkt  = wqt + 1048576;
  unsigned short* wvt  = wkt + 1048576;             // [64][1024]
  unsigned short* wot  = wvt + 65536;               // [1024][64]
  unsigned short* vst  = wot + 65536;               // [B][64][S]
  unsigned short* headb= vst + 262144;              // [4096][64]
  float* recip = (float*)(headb + 262144);          // [B*H*S]

  // bf16 q,k copies live in the am region of d_out (dead before k_attn writes am)
  unsigned short* qb = (unsigned short*)am;         // [4096][1024]
  unsigned short* kb = qb + 4194304;
  // split-K f32 partials [4][4096][64] live in the out region (dead until k_out)
  float* part = out;

  k_prep<<<4384, 256, 0, stream>>>(q, k, Wq, Wk, Wv, Wo, qb, kb, wqt, wkt, wvt, wot);
  k_gemm_qk<<<512, 256, 0, stream>>>(qb, kb, wqt, wkt, qsb, ksb);
  k_pv<<<dim3(64, 4), 256, 0, stream>>>(v, wvt, part);
  k_vred<<<1024, 256, 0, stream>>>(part, vst);
  k_denom<<<512, 512, 0, stream>>>(qsb, ksb, recip);
  k_attn<<<512, 512, 0, stream>>>(qsb, ksb, recip, am);
  k_hpart<<<dim3(64, 4), 256, 0, stream>>>(am, vst, part);
  k_hred<<<1024, 256, 0, stream>>>(part, headb);
  k_out<<<dim3(8, 32, 2), 256, 0, stream>>>(headb, wot, out);
}

// Round 14
// 234.325 us; speedup vs baseline: 1.2069x; 1.0124x over previous
//
#include <hip/hip_runtime.h>

// B=2, S=2048, D=1024, H=16, DK=64
// out = attn_mean @ vs @ Wo  (Wv shared across heads => mean_h(attn_h @ vs) = attn_mean @ vs)
// attn_mean[b,s,t] = (1/H) sum_h exp(score)/denom  -- no max-subtraction (scores bounded ~|2.5|)
// qs/ks layout: [b*S+s][h*64+dk]  (concatenated-head GEMM output)
// All LDS tiles are FRAGMENT-MAJOR: 16B-unit index = tile*64 + quad*16 + l15
//   -> reader addr = tilebase + lane*16B, conflict-free for ds_read_b128.
// r14 = r13 (best, 237.2us) + BLOCK-PARTITION FUSION of independent kernels:
//   k_gemm_qk(512blk) + k_pv(256blk) -> k_qkpv(768blk, branch on blockIdx) -- pv work
//   co-schedules into gemm's free wave slots (gemm = 2 blocks/CU, LDS cap 6/CU).
//   k_denom(512blk) + k_vred -> k_denomv(1024blk @512thr) -- vred fills denom's slots.
// No ordering needed between merged halves (data-independent); 2 fewer launches.
#define B_ 2
#define S_ 2048
#define D_ 1024
#define H_ 16
#define DK_ 64

typedef __bf16 bf8 __attribute__((ext_vector_type(8)));
typedef float f4 __attribute__((ext_vector_type(4)));
typedef unsigned short u16x8 __attribute__((ext_vector_type(8)));

__device__ __forceinline__ unsigned short f2bf_bits(float f) {
  unsigned int u = __float_as_uint(f);
  return (unsigned short)((u + 0x7fffu + ((u >> 16) & 1u)) >> 16);
}

__device__ __forceinline__ bf8 pack_bf8(f4 lo, f4 hi) {
  u16x8 u;
  u[0] = f2bf_bits(lo[0]); u[1] = f2bf_bits(lo[1]);
  u[2] = f2bf_bits(lo[2]); u[3] = f2bf_bits(lo[3]);
  u[4] = f2bf_bits(hi[0]); u[5] = f2bf_bits(hi[1]);
  u[6] = f2bf_bits(hi[2]); u[7] = f2bf_bits(hi[3]);
  union { u16x8 u; bf8 b; } x; x.u = u; return x.b;
}

__device__ __forceinline__ bf8 ldb(const unsigned short* p) {
  return *reinterpret_cast<const bf8*>(p);
}

__device__ __forceinline__ void stage16(const void* g, void* l) {
  __builtin_amdgcn_global_load_lds(
      (const __attribute__((address_space(1))) void*)g,
      (__attribute__((address_space(3))) void*)l, 16, 0, 0);
}

#define MFMA(a, b, c) __builtin_amdgcn_mfma_f32_16x16x32_bf16((a), (b), (c), 0, 0, 0)

// ---- merged prep: cast q,k -> bf16 rows; LDS-tiled transpose-cast weights ----
// blocks 0..4095: cast q/k | 4096..4351: wq/wk 64x64 tiles | 4352..4367: wv | 4368..4383: wo
__global__ void k_prep(const float* __restrict__ q, const float* __restrict__ k,
                       const float* __restrict__ wq, const float* __restrict__ wk,
                       const float* __restrict__ wv, const float* __restrict__ wo,
                       unsigned short* __restrict__ qb, unsigned short* __restrict__ kb,
                       unsigned short* __restrict__ wqt, unsigned short* __restrict__ wkt,
                       unsigned short* __restrict__ wvt, unsigned short* __restrict__ wot) {
  __shared__ float tl[64 * 65];
  int bid = blockIdx.x, tid = threadIdx.x;
  const int rr = tid >> 6, cc = tid & 63;
  if (bid < 4096) {
    int which = bid >> 11;
    long i = ((long)(bid & 2047) * 256 + tid) * 8;
    const float* src = which ? k : q;
    unsigned short* dst = which ? kb : qb;
    f4 lo = *reinterpret_cast<const f4*>(src + i);
    f4 hi = *reinterpret_cast<const f4*>(src + i + 4);
    *reinterpret_cast<bf8*>(dst + i) = pack_bf8(lo, hi);
  } else if (bid < 4352) {
    // Wq/Wk [h][d][n=dk] -> [h][n][d], 64x64 f32 tile via LDS (coalesced both ways)
    int blk = bid - 4096;
    int h = blk >> 4, d0 = (blk & 15) * 64;
    for (int m = 0; m < 2; ++m) {
      const float* src = m ? wk : wq;
      unsigned short* dst = m ? wkt : wqt;
      if (m) __syncthreads();
#pragma unroll
      for (int it = 0; it < 16; ++it) {
        int d = it * 4 + rr;
        tl[cc * 65 + d] = src[(long)h * 65536 + (d0 + d) * 64 + cc];
      }
      __syncthreads();
#pragma unroll
      for (int it = 0; it < 16; ++it) {
        int n = it * 4 + rr;
        dst[(long)h * 65536 + n * 1024 + d0 + cc] = f2bf_bits(tl[n * 65 + cc]);
      }
    }
  } else if (bid < 4368) {
    // Wv [d][n=dk] -> [n][d]
    int d0 = (bid - 4352) * 64;
#pragma unroll
    for (int it = 0; it < 16; ++it) {
      int d = it * 4 + rr;
      tl[cc * 65 + d] = wv[(long)(d0 + d) * 64 + cc];
    }
    __syncthreads();
#pragma unroll
    for (int it = 0; it < 16; ++it) {
      int n = it * 4 + rr;
      wvt[(long)n * 1024 + d0 + cc] = f2bf_bits(tl[n * 65 + cc]);
    }
  } else {
    // Wo [kk][dd] -> [dd][kk]
    int d0 = (bid - 4368) * 64;
#pragma unroll
    for (int it = 0; it < 16; ++it) {
      int kk = it * 4 + rr;
      tl[cc * 65 + kk] = wo[(long)kk * 1024 + d0 + cc];   // tl[ddl][kk]
    }
    __syncthreads();
#pragma unroll
    for (int it = 0; it < 16; ++it) {
      int ddl = it * 4 + rr;
      wot[(long)(d0 + ddl) * 64 + cc] = f2bf_bits(tl[ddl * 65 + cc]);
    }
  }
}

// ---- FUSED: GEMM qs/ks (blocks 0..511) + V-projection split-K (blocks 512..767) ----
// GEMM: C[4096][1024] = X @ W^T, 128x128 tile, BK=32; XCD-swizzled; 3-buffer LDS rotation
// with counted vmcnt(4) (r12/r13, verified). PV: partial[kc][row][64] f32, kc chunk 256.
// PV blocks fill the gemm blocks' free wave slots (gemm = 2 blocks/CU resident).
__global__ __launch_bounds__(256) void k_qkpv(
    const unsigned short* __restrict__ qb, const unsigned short* __restrict__ kb,
    const unsigned short* __restrict__ wqt, const unsigned short* __restrict__ wkt,
    unsigned short* __restrict__ qsb, unsigned short* __restrict__ ksb,
    const float* __restrict__ v, const unsigned short* __restrict__ wvt,
    float* __restrict__ pv) {
  __shared__ unsigned short lds[24576];         // gemm: 3 x (A 8 tiles @0, B 8 tiles @4096)
  const int tid = threadIdx.x, wave = tid >> 6, lane = tid & 63;
  const int l15 = lane & 15, quad = lane >> 4;

  if (blockIdx.x >= 512) {
    // ---- PV branch (256 blocks): grid was (64 rowgroups, 4 kc) ----
    const int bid2 = blockIdx.x - 512;
    const int rg = bid2 & 63, kc = bid2 >> 6;
    const int row0 = rg * 64 + wave * 16;
    const float* arow = v + (long)(row0 + l15) * D_ + kc * 256 + quad * 8;
    const unsigned short* wbase = wvt + kc * 256 + quad * 8;
    f4 acc[4];
    for (int i = 0; i < 4; ++i) acc[i] = f4{0.f, 0.f, 0.f, 0.f};
    for (int k0 = 0; k0 < 256; k0 += 32) {
      f4 alo = *reinterpret_cast<const f4*>(arow + k0);
      f4 ahi = *reinterpret_cast<const f4*>(arow + k0 + 4);
      bf8 a = pack_bf8(alo, ahi);
#pragma unroll
      for (int i = 0; i < 4; ++i) {
        bf8 bf = ldb(wbase + (long)(i * 16 + l15) * D_ + k0);
        acc[i] = MFMA(a, bf, acc[i]);
      }
    }
#pragma unroll
    for (int i = 0; i < 4; ++i)
#pragma unroll
      for (int r = 0; r < 4; ++r)
        pv[((long)kc * 4096 + row0 + quad * 4 + r) * 64 + i * 16 + l15] = acc[i][r];
    return;
  }

  // ---- GEMM branch (512 blocks), r13 structure verbatim ----
  const int n = blockIdx.x, xcd = n & 7, slot = n >> 3;   // slot 0..63
  const int which = xcd >> 2;                              // 0..1
  const int m0 = (((xcd & 3) << 3) | (slot & 7)) * 128;    // 32 m-tiles
  const int n0 = (slot >> 3) * 128;                        // 8 n-tiles
  const unsigned short* A = which ? kb : qb;
  const unsigned short* W = which ? wkt : wqt;
  unsigned short* C = which ? ksb : qsb;
  const float scale = which ? 1.0f : 0.18033688011112042f;  // log2(e)/8 folded into qs
  const int wr = wave >> 1, wc = wave & 1;

  f4 acc[4][4];
#pragma unroll
  for (int i = 0; i < 4; ++i)
#pragma unroll
    for (int j = 0; j < 4; ++j) acc[i][j] = f4{0.f, 0.f, 0.f, 0.f};

  // staging decode: u = i*256+tid; tile=u>>6 (st + i*4), quad=(u>>4)&3, l15=u&15
  const int sl15 = tid & 15, squad = (tid >> 4) & 3, st = tid >> 6;
  const unsigned short* gA = A + (long)(m0 + st * 16 + sl15) * D_ + squad * 8;
  const unsigned short* gB = W + (long)(n0 + st * 16 + sl15) * D_ + squad * 8;

  // prologue: stage k-tiles 0 (buf0) and 1 (buf1); wait only for tile 0
  stage16(gA, lds + tid * 8);
  stage16(gA + 64 * D_, lds + 2048 + tid * 8);
  stage16(gB, lds + 4096 + tid * 8);
  stage16(gB + 64 * D_, lds + 6144 + tid * 8);
  stage16(gA + 32, lds + 8192 + tid * 8);
  stage16(gA + 64 * D_ + 32, lds + 10240 + tid * 8);
  stage16(gB + 32, lds + 12288 + tid * 8);
  stage16(gB + 64 * D_ + 32, lds + 14336 + tid * 8);
  asm volatile("s_waitcnt vmcnt(4)" ::: "memory");
  __builtin_amdgcn_s_barrier();
  int rd = 0;

  for (int it = 0; it < 32; ++it) {
    if (it + 2 < 32) {
      const int k2 = (it + 2) * 32;
      int wb = rd + 2; if (wb >= 3) wb -= 3;
      unsigned short* nb = lds + wb * 8192;
      stage16(gA + k2, nb + tid * 8);
      stage16(gA + 64 * D_ + k2, nb + 2048 + tid * 8);
      stage16(gB + k2, nb + 4096 + tid * 8);
      stage16(gB + 64 * D_ + k2, nb + 6144 + tid * 8);
    }
    const unsigned short* base = lds + rd * 8192;
    __builtin_amdgcn_s_setprio(1);
    bf8 aF[4], bF[4];
#pragma unroll
    for (int mi = 0; mi < 4; ++mi)
      aF[mi] = ldb(base + (wr * 4 + mi) * 512 + lane * 8);
#pragma unroll
    for (int ni = 0; ni < 4; ++ni)
      bF[ni] = ldb(base + 4096 + (wc * 4 + ni) * 512 + lane * 8);
#pragma unroll
    for (int mi = 0; mi < 4; ++mi)
#pragma unroll
      for (int ni = 0; ni < 4; ++ni)
        acc[mi][ni] = MFMA(aF[mi], bF[ni], acc[mi][ni]);
    __builtin_amdgcn_s_setprio(0);
    if (it + 1 < 32) {
      if (it + 2 < 32)
        asm volatile("s_waitcnt vmcnt(4)" ::: "memory");   // tile it+1 landed; it+2 in flight
      else
        asm volatile("s_waitcnt vmcnt(0)" ::: "memory");   // drain for final tile
      __builtin_amdgcn_s_barrier();
      rd = (rd + 1 == 3) ? 0 : rd + 1;
    }
  }
#pragma unroll
  for (int mi = 0; mi < 4; ++mi)
#pragma unroll
    for (int r = 0; r < 4; ++r) {
      long row = m0 + wr * 64 + mi * 16 + quad * 4 + r;
#pragma unroll
      for (int ni = 0; ni < 4; ++ni)
        C[row * D_ + n0 + wc * 64 + ni * 16 + l15] = f2bf_bits(acc[mi][ni][r] * scale);
    }
}

// ---- FUSED: denom pass (blocks 0..511) + vred (blocks 512..1023, 512 thr each) ----
// denom: recip[b,h,s] = 1/(H * sum_t exp2(qs.ks)); XCD-swizzled (r8), r9 structure.
// vred: reduce 4 k-partials -> vst[b][dk][t] bf16; fills denom's free wave slots.
__global__ __launch_bounds__(512) void k_denomv(
    const unsigned short* __restrict__ qsb, const unsigned short* __restrict__ ksb,
    float* __restrict__ recip,
    const float* __restrict__ pv, unsigned short* __restrict__ vst) {
  __shared__ unsigned short lds[16384];         // denom: 2 x (128 t-rows x 64 dk)
  const int tid = threadIdx.x, wave = tid >> 6, lane = tid & 63;
  const int l15 = lane & 15, quad = lane >> 4;

  if (blockIdx.x >= 512) {
    // ---- vred branch: e = (bid-512)*512 + tid, total 262144 ----
    int e = (blockIdx.x - 512) * 512 + tid;    // e = (b*64+dk)*2048 + t
    int t = e & 2047, dk = (e >> 11) & 63, b = e >> 17;
    long row = (long)b * S_ + t;
    float s = pv[row * 64 + dk] + pv[(4096 + row) * 64 + dk] +
              pv[(8192 + row) * 64 + dk] + pv[(12288 + row) * 64 + dk];
    vst[e] = f2bf_bits(s);
    return;
  }

  // ---- denom branch (512 blocks), r13 structure verbatim ----
  const int n = blockIdx.x, xcd = n & 7, slot = n >> 3;
  const int b = xcd >> 2;
  const int h = ((xcd & 3) << 2) | (slot & 3);
  const int stile = slot >> 2;
  const int s0 = stile * 128 + wave * 16;

  const unsigned short* qrow = qsb + ((long)(b * S_) + s0 + l15) * D_ + h * 64 + quad * 8;
  bf8 a0 = ldb(qrow);
  bf8 a1 = ldb(qrow + 32);

  // staging decode for u = tid (sh2=0) and u = tid+512 (sh2=1): stt=(tid>>6)&7
  const int sl15 = tid & 15, squad = (tid >> 4) & 3, stt = (tid >> 6) & 7;
  const unsigned short* g0 =
      ksb + ((long)(b * S_) + stt * 16 + sl15) * D_ + h * 64 + squad * 8;

  // prologue: stage tile 0 into buf0
  stage16(g0, lds + tid * 8);
  stage16(g0 + 32, lds + 4096 + tid * 8);
  asm volatile("s_waitcnt vmcnt(0)" ::: "memory");
  __builtin_amdgcn_s_barrier();
  int cur = 0;

  f4 sum = f4{0.f, 0.f, 0.f, 0.f};
  for (int it = 0; it < 16; ++it) {
    if (it + 1 < 16) {
      const unsigned short* gn = g0 + (long)(it + 1) * 128 * D_;
      unsigned short* nb = lds + (cur ^ 1) * 8192;
      stage16(gn, nb + tid * 8);
      stage16(gn + 32, nb + 4096 + tid * 8);
    }
    const unsigned short* base = lds + cur * 8192;
    __builtin_amdgcn_s_setprio(1);
#pragma unroll
    for (int tt = 0; tt < 8; ++tt) {
      bf8 b0 = ldb(base + tt * 512 + lane * 8);
      bf8 b1 = ldb(base + 4096 + tt * 512 + lane * 8);
      f4 d = f4{0.f, 0.f, 0.f, 0.f};
      d = MFMA(a0, b0, d);
      d = MFMA(a1, b1, d);
#pragma unroll
      for (int r = 0; r < 4; ++r) sum[r] += __builtin_amdgcn_exp2f(d[r]);
    }
    __builtin_amdgcn_s_setprio(0);
    if (it + 1 < 16) {
      asm volatile("s_waitcnt vmcnt(0)" ::: "memory");
      __builtin_amdgcn_s_barrier();
      cur ^= 1;
    }
  }
#pragma unroll
  for (int m = 1; m < 16; m <<= 1) {
#pragma unroll
    for (int r = 0; r < 4; ++r) sum[r] += __shfl_xor(sum[r], m, 64);
  }
  if (l15 == 0) {
    float* rp = recip + (long)(b * H_ + h) * S_ + s0 + quad * 4;
#pragma unroll
    for (int r = 0; r < 4; ++r) rp[r] = 1.0f / (16.0f * sum[r]);
  }
}

// ---- pass 2: attn_mean[b,s,t] = sum_h recip[b,h,s]*exp2(score) ----
// 1D grid 512, block 512 (8 waves); XCD-swizzled decode (r8) + Q-frag register prefetch
// (r9, best measured): load h+1's a0n/a1n/rpn BEFORE its stage16 (sched_barrier pins
// order), compute consumes preloaded regs, rotate after barrier.
__global__ __launch_bounds__(512) void k_attn(
    const unsigned short* __restrict__ qsb, const unsigned short* __restrict__ ksb,
    const float* __restrict__ recip, float* __restrict__ am) {
  __shared__ unsigned short lds[16384];         // 2 x (128 t-rows x 64 dk) per head
  const int tid = threadIdx.x, wave = tid >> 6, lane = tid & 63;
  const int l15 = lane & 15, quad = lane >> 4;
  const int n = blockIdx.x, xcd = n & 7, slot = n >> 3;
  const int b = xcd >> 2;
  const int tchunk = ((xcd & 1) << 3) | (slot & 7);
  const int stile = (((xcd >> 1) & 1) << 3) | (slot >> 3);
  const int s0 = stile * 128 + wave * 16;
  const int t0c = tchunk * 128;

  f4 acc[8];
#pragma unroll
  for (int tt = 0; tt < 8; ++tt) acc[tt] = f4{0.f, 0.f, 0.f, 0.f};

  const unsigned short* qbase = qsb + ((long)(b * S_) + s0 + l15) * D_ + quad * 8;
  // staging decode for u = tid (sh2=0) and u = tid+512 (sh2=1): stt=(tid>>6)&7
  const int sl15 = tid & 15, squad = (tid >> 4) & 3, stt = (tid >> 6) & 7;
  const unsigned short* g0 =
      ksb + ((long)(b * S_) + t0c + stt * 16 + sl15) * D_ + squad * 8;
  const float* rbase = recip + (long)(b * H_) * S_ + s0 + quad * 4;

  // prologue: stage head 0 into buf0; load head 0's Q-frags + recip
  stage16(g0, lds + tid * 8);
  stage16(g0 + 32, lds + 4096 + tid * 8);
  bf8 a0 = ldb(qbase);
  bf8 a1 = ldb(qbase + 32);
  f4 rp = *reinterpret_cast<const f4*>(rbase);
  asm volatile("s_waitcnt vmcnt(0)" ::: "memory");
  __builtin_amdgcn_s_barrier();
  int cur = 0;

  for (int h = 0; h < H_; ++h) {
    bf8 a0n, a1n;
    f4 rpn;
    if (h + 1 < H_) {
      // register prefetch for head h+1 -- issued BEFORE the stage16s (in-order vmcnt)
      a0n = ldb(qbase + (h + 1) * 64);
      a1n = ldb(qbase + (h + 1) * 64 + 32);
      rpn = *reinterpret_cast<const f4*>(rbase + (long)(h + 1) * S_);
      __builtin_amdgcn_sched_barrier(0);        // pin: reg loads above, staging below
      const unsigned short* gn = g0 + (h + 1) * 64;
      unsigned short* nb = lds + (cur ^ 1) * 8192;
      stage16(gn, nb + tid * 8);
      stage16(gn + 32, nb + 4096 + tid * 8);
    }
    const unsigned short* base = lds + cur * 8192;
    __builtin_amdgcn_s_setprio(1);
#pragma unroll
    for (int tt = 0; tt < 8; ++tt) {
      bf8 b0 = ldb(base + tt * 512 + lane * 8);
      bf8 b1 = ldb(base + 4096 + tt * 512 + lane * 8);
      f4 d = f4{0.f, 0.f, 0.f, 0.f};
      d = MFMA(a0, b0, d);
      d = MFMA(a1, b1, d);
#pragma unroll
      for (int r = 0; r < 4; ++r) acc[tt][r] += rp[r] * __builtin_amdgcn_exp2f(d[r]);
    }
    __builtin_amdgcn_s_setprio(0);
    if (h + 1 < H_) {
      asm volatile("s_waitcnt vmcnt(0)" ::: "memory");
      __builtin_amdgcn_s_barrier();
      cur ^= 1;
      a0 = a0n;
      a1 = a1n;
      rp = rpn;
    }
  }
  float* obase = am + ((long)b * S_ + s0 + quad * 4) * S_ + t0c + l15;
#pragma unroll
  for (int tt = 0; tt < 8; ++tt)
#pragma unroll
    for (int r = 0; r < 4; ++r) obase[(long)r * S_ + tt * 16] = acc[tt][r];
}

// ---- head split-K: ph[kc][row][64] f32 = am-chunk @ vs-chunk, kc chunk = 512 t ----
// grid (64 rowgroups, 4 kc), block 256
__global__ __launch_bounds__(256) void k_hpart(
    const float* __restrict__ am, const unsigned short* __restrict__ vst,
    float* __restrict__ ph) {
  const int tid = threadIdx.x, wave = tid >> 6, lane = tid & 63;
  const int l15 = lane & 15, quad = lane >> 4;
  const int rg = blockIdx.x, kc = blockIdx.y;
  const int row0 = rg * 64 + wave * 16;
  const int b = row0 >> 11;
  const float* arow = am + (long)(row0 + l15) * S_ + kc * 512 + quad * 8;
  const unsigned short* vb = vst + (long)b * DK_ * S_ + kc * 512 + quad * 8;
  f4 acc[4];
  for (int i = 0; i < 4; ++i) acc[i] = f4{0.f, 0.f, 0.f, 0.f};
  for (int t0 = 0; t0 < 512; t0 += 32) {
    f4 alo = *reinterpret_cast<const f4*>(arow + t0);
    f4 ahi = *reinterpret_cast<const f4*>(arow + t0 + 4);
    bf8 a = pack_bf8(alo, ahi);
#pragma unroll
    for (int i = 0; i < 4; ++i) {
      bf8 bf = ldb(vb + (long)(i * 16 + l15) * S_ + t0);
      acc[i] = MFMA(a, bf, acc[i]);
    }
  }
#pragma unroll
  for (int i = 0; i < 4; ++i)
#pragma unroll
    for (int r = 0; r < 4; ++r)
      ph[((long)kc * 4096 + row0 + quad * 4 + r) * 64 + i * 16 + l15] = acc[i][r];
}

// reduce -> headb bf16 [row][64] (fully coalesced)
__global__ void k_hred(const float* __restrict__ ph, unsigned short* __restrict__ headb) {
  int e = blockIdx.x * 256 + threadIdx.x;      // e = row*64 + dk
  float s = ph[e] + ph[e + 4096 * 64] + ph[e + 2 * 4096 * 64] + ph[e + 3 * 4096 * 64];
  headb[e] = f2bf_bits(s);
}

// ---- out = head @ Wo ----
// grid (8 d-chunks of 128, 32 s-tiles of 64, B), block 256
__global__ __launch_bounds__(256) void k_out(
    const unsigned short* __restrict__ head, const unsigned short* __restrict__ wot,
    float* __restrict__ out) {
  const int tid = threadIdx.x, wave = tid >> 6, lane = tid & 63;
  const int l15 = lane & 15, quad = lane >> 4;
  const int dchunk = blockIdx.x, stile = blockIdx.y, b = blockIdx.z;
  const int s0 = stile * 64 + wave * 16;
  const int n0 = dchunk * 128;
  const unsigned short* hrow = head + ((long)b * S_ + s0 + l15) * DK_ + quad * 8;
  bf8 a0 = ldb(hrow);
  bf8 a1 = ldb(hrow + 32);
  const unsigned short* wb = wot + quad * 8;
  float* obase = out + ((long)b * S_ + s0 + quad * 4) * D_ + n0 + l15;
#pragma unroll
  for (int i = 0; i < 8; ++i) {
    const unsigned short* wp = wb + (long)(n0 + i * 16 + l15) * DK_;
    bf8 b0 = ldb(wp);
    bf8 b1 = ldb(wp + 32);
    f4 d = f4{0.f, 0.f, 0.f, 0.f};
    d = MFMA(a0, b0, d);
    d = MFMA(a1, b1, d);
#pragma unroll
    for (int r = 0; r < 4; ++r) obase[(long)r * D_ + i * 16] = d[r];
  }
}

extern "C" void kernel_launch(void* const* d_in, const int* in_sizes, int n_in,
                              void* d_out, int out_size, void* d_ws, size_t ws_size,
                              hipStream_t stream) {
  const float* q  = (const float*)d_in[0];
  const float* k  = (const float*)d_in[1];
  const float* v  = (const float*)d_in[2];
  const float* Wq = (const float*)d_in[3];
  const float* Wk = (const float*)d_in[4];
  const float* Wv = (const float*)d_in[5];
  const float* Wo = (const float*)d_in[6];

  float* out = (float*)d_out;                       // [B,S,D] = 4,194,304 f32
  float* am  = out + (long)B_ * S_ * D_;            // [B,S,S] = 8,388,608 f32

  // workspace (~22.5 MB)
  unsigned short* qsb  = (unsigned short*)d_ws;     // [4096][1024]
  unsigned short* ksb  = qsb + 4194304;
  unsigned short* wqt  = ksb + 4194304;             // [1024][1024]
  unsigned short* wkt  = wqt + 1048576;
  unsigned short* wvt  = wkt + 1048576;             // [64][1024]
  unsigned short* wot  = wvt + 65536;               // [1024][64]
  unsigned short* vst  = wot + 65536;               // [B][64][S]
  unsigned short* headb= vst + 262144;              // [4096][64]
  float* recip = (float*)(headb + 262144);          // [B*H*S]

  // bf16 q,k copies live in the am region of d_out (dead before k_attn writes am)
  unsigned short* qb = (unsigned short*)am;         // [4096][1024]
  unsigned short* kb = qb + 4194304;
  // split-K f32 partials [4][4096][64] live in the out region (dead until k_out)
  float* part = out;

  k_prep<<<4384, 256, 0, stream>>>(q, k, Wq, Wk, Wv, Wo, qb, kb, wqt, wkt, wvt, wot);
  k_qkpv<<<768, 256, 0, stream>>>(qb, kb, wqt, wkt, qsb, ksb, v, wvt, part);
  k_denomv<<<1024, 512, 0, stream>>>(qsb, ksb, recip, part, vst);
  k_attn<<<512, 512, 0, stream>>>(qsb, ksb, recip, am);
  k_hpart<<<dim3(64, 4), 256, 0, stream>>>(am, vst, part);
  k_hred<<<1024, 256, 0, stream>>>(part, headb);
  k_out<<<dim3(8, 32, 2), 256, 0, stream>>>(headb, wot, out);
}

// Round 15
// 232.787 us; speedup vs baseline: 1.2148x; 1.0066x over previous
//
#include <hip/hip_runtime.h>

// B=2, S=2048, D=1024, H=16, DK=64
// out = attn_mean @ vs @ Wo  (Wv shared across heads => mean_h(attn_h @ vs) = attn_mean @ vs)
// attn_mean[b,s,t] = (1/H) sum_h exp(score)/denom  -- no max-subtraction (scores bounded ~|2.5|)
// qs/ks layout: [b*S+s][h*64+dk]  (concatenated-head GEMM output)
// All LDS tiles are FRAGMENT-MAJOR: 16B-unit index = tile*64 + quad*16 + l15
//   -> reader addr = tilebase + lane*16B, conflict-free for ds_read_b128.
// r15 = r14 (best, 234.3us) + PV FUSION INTO k_attn: k_hpart re-read the 32MB am tile
// that k_attn still held in registers, and k_attn is stall-bound (<30% all pipes) with
// slack to absorb the PV MFMAs. Epilogue: reuse dead 32KB K-staging LDS as bf16 P-tile
// (128x128 = exact fit), re-read as A-frags, 16 MFMA vs vst, atomicAdd into f32
// headf[4096][64] (1MB, dead wqt region; zeroed by k_denomv's extra 512 blocks;
// device-scope atomics are XCD-coherent). k_hpart + k_hred DELETED; k_out reads
// headf f32 + casts inline. Same math path (f32 am -> bf16 P -> MFMA) as hpart.
#define B_ 2
#define S_ 2048
#define D_ 1024
#define H_ 16
#define DK_ 64

typedef __bf16 bf8 __attribute__((ext_vector_type(8)));
typedef float f4 __attribute__((ext_vector_type(4)));
typedef unsigned short u16x8 __attribute__((ext_vector_type(8)));

__device__ __forceinline__ unsigned short f2bf_bits(float f) {
  unsigned int u = __float_as_uint(f);
  return (unsigned short)((u + 0x7fffu + ((u >> 16) & 1u)) >> 16);
}

__device__ __forceinline__ bf8 pack_bf8(f4 lo, f4 hi) {
  u16x8 u;
  u[0] = f2bf_bits(lo[0]); u[1] = f2bf_bits(lo[1]);
  u[2] = f2bf_bits(lo[2]); u[3] = f2bf_bits(lo[3]);
  u[4] = f2bf_bits(hi[0]); u[5] = f2bf_bits(hi[1]);
  u[6] = f2bf_bits(hi[2]); u[7] = f2bf_bits(hi[3]);
  union { u16x8 u; bf8 b; } x; x.u = u; return x.b;
}

__device__ __forceinline__ bf8 ldb(const unsigned short* p) {
  return *reinterpret_cast<const bf8*>(p);
}

__device__ __forceinline__ void stage16(const void* g, void* l) {
  __builtin_amdgcn_global_load_lds(
      (const __attribute__((address_space(1))) void*)g,
      (__attribute__((address_space(3))) void*)l, 16, 0, 0);
}

#define MFMA(a, b, c) __builtin_amdgcn_mfma_f32_16x16x32_bf16((a), (b), (c), 0, 0, 0)

// ---- merged prep: cast q,k -> bf16 rows; LDS-tiled transpose-cast weights ----
// blocks 0..4095: cast q/k | 4096..4351: wq/wk 64x64 tiles | 4352..4367: wv | 4368..4383: wo
__global__ void k_prep(const float* __restrict__ q, const float* __restrict__ k,
                       const float* __restrict__ wq, const float* __restrict__ wk,
                       const float* __restrict__ wv, const float* __restrict__ wo,
                       unsigned short* __restrict__ qb, unsigned short* __restrict__ kb,
                       unsigned short* __restrict__ wqt, unsigned short* __restrict__ wkt,
                       unsigned short* __restrict__ wvt, unsigned short* __restrict__ wot) {
  __shared__ float tl[64 * 65];
  int bid = blockIdx.x, tid = threadIdx.x;
  const int rr = tid >> 6, cc = tid & 63;
  if (bid < 4096) {
    int which = bid >> 11;
    long i = ((long)(bid & 2047) * 256 + tid) * 8;
    const float* src = which ? k : q;
    unsigned short* dst = which ? kb : qb;
    f4 lo = *reinterpret_cast<const f4*>(src + i);
    f4 hi = *reinterpret_cast<const f4*>(src + i + 4);
    *reinterpret_cast<bf8*>(dst + i) = pack_bf8(lo, hi);
  } else if (bid < 4352) {
    // Wq/Wk [h][d][n=dk] -> [h][n][d], 64x64 f32 tile via LDS (coalesced both ways)
    int blk = bid - 4096;
    int h = blk >> 4, d0 = (blk & 15) * 64;
    for (int m = 0; m < 2; ++m) {
      const float* src = m ? wk : wq;
      unsigned short* dst = m ? wkt : wqt;
      if (m) __syncthreads();
#pragma unroll
      for (int it = 0; it < 16; ++it) {
        int d = it * 4 + rr;
        tl[cc * 65 + d] = src[(long)h * 65536 + (d0 + d) * 64 + cc];
      }
      __syncthreads();
#pragma unroll
      for (int it = 0; it < 16; ++it) {
        int n = it * 4 + rr;
        dst[(long)h * 65536 + n * 1024 + d0 + cc] = f2bf_bits(tl[n * 65 + cc]);
      }
    }
  } else if (bid < 4368) {
    // Wv [d][n=dk] -> [n][d]
    int d0 = (bid - 4352) * 64;
#pragma unroll
    for (int it = 0; it < 16; ++it) {
      int d = it * 4 + rr;
      tl[cc * 65 + d] = wv[(long)(d0 + d) * 64 + cc];
    }
    __syncthreads();
#pragma unroll
    for (int it = 0; it < 16; ++it) {
      int n = it * 4 + rr;
      wvt[(long)n * 1024 + d0 + cc] = f2bf_bits(tl[n * 65 + cc]);
    }
  } else {
    // Wo [kk][dd] -> [dd][kk]
    int d0 = (bid - 4368) * 64;
#pragma unroll
    for (int it = 0; it < 16; ++it) {
      int kk = it * 4 + rr;
      tl[cc * 65 + kk] = wo[(long)kk * 1024 + d0 + cc];   // tl[ddl][kk]
    }
    __syncthreads();
#pragma unroll
    for (int it = 0; it < 16; ++it) {
      int ddl = it * 4 + rr;
      wot[(long)(d0 + ddl) * 64 + cc] = f2bf_bits(tl[ddl * 65 + cc]);
    }
  }
}

// ---- FUSED: GEMM qs/ks (blocks 0..511) + V-projection split-K (blocks 512..767) ----
// GEMM: C[4096][1024] = X @ W^T, 128x128 tile, BK=32; XCD-swizzled; 3-buffer LDS rotation
// with counted vmcnt(4) (r12/r13, verified). PV: partial[kc][row][64] f32, kc chunk 256.
__global__ __launch_bounds__(256) void k_qkpv(
    const unsigned short* __restrict__ qb, const unsigned short* __restrict__ kb,
    const unsigned short* __restrict__ wqt, const unsigned short* __restrict__ wkt,
    unsigned short* __restrict__ qsb, unsigned short* __restrict__ ksb,
    const float* __restrict__ v, const unsigned short* __restrict__ wvt,
    float* __restrict__ pv) {
  __shared__ unsigned short lds[24576];         // gemm: 3 x (A 8 tiles @0, B 8 tiles @4096)
  const int tid = threadIdx.x, wave = tid >> 6, lane = tid & 63;
  const int l15 = lane & 15, quad = lane >> 4;

  if (blockIdx.x >= 512) {
    // ---- PV branch (256 blocks): grid was (64 rowgroups, 4 kc) ----
    const int bid2 = blockIdx.x - 512;
    const int rg = bid2 & 63, kc = bid2 >> 6;
    const int row0 = rg * 64 + wave * 16;
    const float* arow = v + (long)(row0 + l15) * D_ + kc * 256 + quad * 8;
    const unsigned short* wbase = wvt + kc * 256 + quad * 8;
    f4 acc[4];
    for (int i = 0; i < 4; ++i) acc[i] = f4{0.f, 0.f, 0.f, 0.f};
    for (int k0 = 0; k0 < 256; k0 += 32) {
      f4 alo = *reinterpret_cast<const f4*>(arow + k0);
      f4 ahi = *reinterpret_cast<const f4*>(arow + k0 + 4);
      bf8 a = pack_bf8(alo, ahi);
#pragma unroll
      for (int i = 0; i < 4; ++i) {
        bf8 bf = ldb(wbase + (long)(i * 16 + l15) * D_ + k0);
        acc[i] = MFMA(a, bf, acc[i]);
      }
    }
#pragma unroll
    for (int i = 0; i < 4; ++i)
#pragma unroll
      for (int r = 0; r < 4; ++r)
        pv[((long)kc * 4096 + row0 + quad * 4 + r) * 64 + i * 16 + l15] = acc[i][r];
    return;
  }

  // ---- GEMM branch (512 blocks), r13 structure verbatim ----
  const int n = blockIdx.x, xcd = n & 7, slot = n >> 3;   // slot 0..63
  const int which = xcd >> 2;                              // 0..1
  const int m0 = (((xcd & 3) << 3) | (slot & 7)) * 128;    // 32 m-tiles
  const int n0 = (slot >> 3) * 128;                        // 8 n-tiles
  const unsigned short* A = which ? kb : qb;
  const unsigned short* W = which ? wkt : wqt;
  unsigned short* C = which ? ksb : qsb;
  const float scale = which ? 1.0f : 0.18033688011112042f;  // log2(e)/8 folded into qs
  const int wr = wave >> 1, wc = wave & 1;

  f4 acc[4][4];
#pragma unroll
  for (int i = 0; i < 4; ++i)
#pragma unroll
    for (int j = 0; j < 4; ++j) acc[i][j] = f4{0.f, 0.f, 0.f, 0.f};

  // staging decode: u = i*256+tid; tile=u>>6 (st + i*4), quad=(u>>4)&3, l15=u&15
  const int sl15 = tid & 15, squad = (tid >> 4) & 3, st = tid >> 6;
  const unsigned short* gA = A + (long)(m0 + st * 16 + sl15) * D_ + squad * 8;
  const unsigned short* gB = W + (long)(n0 + st * 16 + sl15) * D_ + squad * 8;

  // prologue: stage k-tiles 0 (buf0) and 1 (buf1); wait only for tile 0
  stage16(gA, lds + tid * 8);
  stage16(gA + 64 * D_, lds + 2048 + tid * 8);
  stage16(gB, lds + 4096 + tid * 8);
  stage16(gB + 64 * D_, lds + 6144 + tid * 8);
  stage16(gA + 32, lds + 8192 + tid * 8);
  stage16(gA + 64 * D_ + 32, lds + 10240 + tid * 8);
  stage16(gB + 32, lds + 12288 + tid * 8);
  stage16(gB + 64 * D_ + 32, lds + 14336 + tid * 8);
  asm volatile("s_waitcnt vmcnt(4)" ::: "memory");
  __builtin_amdgcn_s_barrier();
  int rd = 0;

  for (int it = 0; it < 32; ++it) {
    if (it + 2 < 32) {
      const int k2 = (it + 2) * 32;
      int wb = rd + 2; if (wb >= 3) wb -= 3;
      unsigned short* nb = lds + wb * 8192;
      stage16(gA + k2, nb + tid * 8);
      stage16(gA + 64 * D_ + k2, nb + 2048 + tid * 8);
      stage16(gB + k2, nb + 4096 + tid * 8);
      stage16(gB + 64 * D_ + k2, nb + 6144 + tid * 8);
    }
    const unsigned short* base = lds + rd * 8192;
    __builtin_amdgcn_s_setprio(1);
    bf8 aF[4], bF[4];
#pragma unroll
    for (int mi = 0; mi < 4; ++mi)
      aF[mi] = ldb(base + (wr * 4 + mi) * 512 + lane * 8);
#pragma unroll
    for (int ni = 0; ni < 4; ++ni)
      bF[ni] = ldb(base + 4096 + (wc * 4 + ni) * 512 + lane * 8);
#pragma unroll
    for (int mi = 0; mi < 4; ++mi)
#pragma unroll
      for (int ni = 0; ni < 4; ++ni)
        acc[mi][ni] = MFMA(aF[mi], bF[ni], acc[mi][ni]);
    __builtin_amdgcn_s_setprio(0);
    if (it + 1 < 32) {
      if (it + 2 < 32)
        asm volatile("s_waitcnt vmcnt(4)" ::: "memory");   // tile it+1 landed; it+2 in flight
      else
        asm volatile("s_waitcnt vmcnt(0)" ::: "memory");   // drain for final tile
      __builtin_amdgcn_s_barrier();
      rd = (rd + 1 == 3) ? 0 : rd + 1;
    }
  }
#pragma unroll
  for (int mi = 0; mi < 4; ++mi)
#pragma unroll
    for (int r = 0; r < 4; ++r) {
      long row = m0 + wr * 64 + mi * 16 + quad * 4 + r;
#pragma unroll
      for (int ni = 0; ni < 4; ++ni)
        C[row * D_ + n0 + wc * 64 + ni * 16 + l15] = f2bf_bits(acc[mi][ni][r] * scale);
    }
}

// ---- FUSED: denom (blocks 0..511) + vred (512..1023) + headf zero (1024..1535) ----
__global__ __launch_bounds__(512) void k_denomv(
    const unsigned short* __restrict__ qsb, const unsigned short* __restrict__ ksb,
    float* __restrict__ recip,
    const float* __restrict__ pv, unsigned short* __restrict__ vst,
    float* __restrict__ headf) {
  __shared__ unsigned short lds[16384];         // denom: 2 x (128 t-rows x 64 dk)
  const int tid = threadIdx.x, wave = tid >> 6, lane = tid & 63;
  const int l15 = lane & 15, quad = lane >> 4;

  if (blockIdx.x >= 1024) {
    // ---- headf zero branch: 512 blocks x 512 thr = 262144 f32 ----
    headf[(blockIdx.x - 1024) * 512 + tid] = 0.f;
    return;
  }
  if (blockIdx.x >= 512) {
    // ---- vred branch: e = (bid-512)*512 + tid, total 262144 ----
    int e = (blockIdx.x - 512) * 512 + tid;    // e = (b*64+dk)*2048 + t
    int t = e & 2047, dk = (e >> 11) & 63, b = e >> 17;
    long row = (long)b * S_ + t;
    float s = pv[row * 64 + dk] + pv[(4096 + row) * 64 + dk] +
              pv[(8192 + row) * 64 + dk] + pv[(12288 + row) * 64 + dk];
    vst[e] = f2bf_bits(s);
    return;
  }

  // ---- denom branch (512 blocks), r13 structure verbatim ----
  const int n = blockIdx.x, xcd = n & 7, slot = n >> 3;
  const int b = xcd >> 2;
  const int h = ((xcd & 3) << 2) | (slot & 3);
  const int stile = slot >> 2;
  const int s0 = stile * 128 + wave * 16;

  const unsigned short* qrow = qsb + ((long)(b * S_) + s0 + l15) * D_ + h * 64 + quad * 8;
  bf8 a0 = ldb(qrow);
  bf8 a1 = ldb(qrow + 32);

  // staging decode for u = tid (sh2=0) and u = tid+512 (sh2=1): stt=(tid>>6)&7
  const int sl15 = tid & 15, squad = (tid >> 4) & 3, stt = (tid >> 6) & 7;
  const unsigned short* g0 =
      ksb + ((long)(b * S_) + stt * 16 + sl15) * D_ + h * 64 + squad * 8;

  // prologue: stage tile 0 into buf0
  stage16(g0, lds + tid * 8);
  stage16(g0 + 32, lds + 4096 + tid * 8);
  asm volatile("s_waitcnt vmcnt(0)" ::: "memory");
  __builtin_amdgcn_s_barrier();
  int cur = 0;

  f4 sum = f4{0.f, 0.f, 0.f, 0.f};
  for (int it = 0; it < 16; ++it) {
    if (it + 1 < 16) {
      const unsigned short* gn = g0 + (long)(it + 1) * 128 * D_;
      unsigned short* nb = lds + (cur ^ 1) * 8192;
      stage16(gn, nb + tid * 8);
      stage16(gn + 32, nb + 4096 + tid * 8);
    }
    const unsigned short* base = lds + cur * 8192;
    __builtin_amdgcn_s_setprio(1);
#pragma unroll
    for (int tt = 0; tt < 8; ++tt) {
      bf8 b0 = ldb(base + tt * 512 + lane * 8);
      bf8 b1 = ldb(base + 4096 + tt * 512 + lane * 8);
      f4 d = f4{0.f, 0.f, 0.f, 0.f};
      d = MFMA(a0, b0, d);
      d = MFMA(a1, b1, d);
#pragma unroll
      for (int r = 0; r < 4; ++r) sum[r] += __builtin_amdgcn_exp2f(d[r]);
    }
    __builtin_amdgcn_s_setprio(0);
    if (it + 1 < 16) {
      asm volatile("s_waitcnt vmcnt(0)" ::: "memory");
      __builtin_amdgcn_s_barrier();
      cur ^= 1;
    }
  }
#pragma unroll
  for (int m = 1; m < 16; m <<= 1) {
#pragma unroll
    for (int r = 0; r < 4; ++r) sum[r] += __shfl_xor(sum[r], m, 64);
  }
  if (l15 == 0) {
    float* rp = recip + (long)(b * H_ + h) * S_ + s0 + quad * 4;
#pragma unroll
    for (int r = 0; r < 4; ++r) rp[r] = 1.0f / (16.0f * sum[r]);
  }
}

// ---- pass 2 + fused PV: attn_mean write + head partial accumulation ----
// 1D grid 512, block 512 (8 waves); XCD swizzle (r8) + Q-frag register prefetch (r9).
// Epilogue: am tile (still in acc regs) -> bf16 P in the dead 32KB K-staging LDS ->
// A-frags -> 16 MFMA vs vst -> atomicAdd into headf (replaces k_hpart's 32MB am re-read).
__global__ __launch_bounds__(512) void k_attn(
    const unsigned short* __restrict__ qsb, const unsigned short* __restrict__ ksb,
    const float* __restrict__ recip, float* __restrict__ am,
    const unsigned short* __restrict__ vst, float* __restrict__ headf) {
  __shared__ unsigned short lds[16384];         // 2 x (128 t-rows x 64 dk) per head
  const int tid = threadIdx.x, wave = tid >> 6, lane = tid & 63;
  const int l15 = lane & 15, quad = lane >> 4;
  const int n = blockIdx.x, xcd = n & 7, slot = n >> 3;
  const int b = xcd >> 2;
  const int tchunk = ((xcd & 1) << 3) | (slot & 7);
  const int stile = (((xcd >> 1) & 1) << 3) | (slot >> 3);
  const int s0 = stile * 128 + wave * 16;
  const int t0c = tchunk * 128;

  f4 acc[8];
#pragma unroll
  for (int tt = 0; tt < 8; ++tt) acc[tt] = f4{0.f, 0.f, 0.f, 0.f};

  const unsigned short* qbase = qsb + ((long)(b * S_) + s0 + l15) * D_ + quad * 8;
  // staging decode for u = tid (sh2=0) and u = tid+512 (sh2=1): stt=(tid>>6)&7
  const int sl15 = tid & 15, squad = (tid >> 4) & 3, stt = (tid >> 6) & 7;
  const unsigned short* g0 =
      ksb + ((long)(b * S_) + t0c + stt * 16 + sl15) * D_ + squad * 8;
  const float* rbase = recip + (long)(b * H_) * S_ + s0 + quad * 4;

  // prologue: stage head 0 into buf0; load head 0's Q-frags + recip
  stage16(g0, lds + tid * 8);
  stage16(g0 + 32, lds + 4096 + tid * 8);
  bf8 a0 = ldb(qbase);
  bf8 a1 = ldb(qbase + 32);
  f4 rp = *reinterpret_cast<const f4*>(rbase);
  asm volatile("s_waitcnt vmcnt(0)" ::: "memory");
  __builtin_amdgcn_s_barrier();
  int cur = 0;

  for (int h = 0; h < H_; ++h) {
    bf8 a0n, a1n;
    f4 rpn;
    if (h + 1 < H_) {
      // register prefetch for head h+1 -- issued BEFORE the stage16s (in-order vmcnt)
      a0n = ldb(qbase + (h + 1) * 64);
      a1n = ldb(qbase + (h + 1) * 64 + 32);
      rpn = *reinterpret_cast<const f4*>(rbase + (long)(h + 1) * S_);
      __builtin_amdgcn_sched_barrier(0);        // pin: reg loads above, staging below
      const unsigned short* gn = g0 + (h + 1) * 64;
      unsigned short* nb = lds + (cur ^ 1) * 8192;
      stage16(gn, nb + tid * 8);
      stage16(gn + 32, nb + 4096 + tid * 8);
    }
    const unsigned short* base = lds + cur * 8192;
    __builtin_amdgcn_s_setprio(1);
#pragma unroll
    for (int tt = 0; tt < 8; ++tt) {
      bf8 b0 = ldb(base + tt * 512 + lane * 8);
      bf8 b1 = ldb(base + 4096 + tt * 512 + lane * 8);
      f4 d = f4{0.f, 0.f, 0.f, 0.f};
      d = MFMA(a0, b0, d);
      d = MFMA(a1, b1, d);
#pragma unroll
      for (int r = 0; r < 4; ++r) acc[tt][r] += rp[r] * __builtin_amdgcn_exp2f(d[r]);
    }
    __builtin_amdgcn_s_setprio(0);
    if (h + 1 < H_) {
      asm volatile("s_waitcnt vmcnt(0)" ::: "memory");
      __builtin_amdgcn_s_barrier();
      cur ^= 1;
      a0 = a0n;
      a1 = a1n;
      rp = rpn;
    }
  }
  // write am (unchanged)
  float* obase = am + ((long)b * S_ + s0 + quad * 4) * S_ + t0c + l15;
#pragma unroll
  for (int tt = 0; tt < 8; ++tt)
#pragma unroll
    for (int r = 0; r < 4; ++r) obase[(long)r * S_ + tt * 16] = acc[tt][r];

  // ---- fused PV epilogue: headf[s][dk] += sum_{t in tile} am[s][t] * vs[t][dk] ----
  __syncthreads();                               // all waves done with K-staging lds
  // P tile bf16 [128 rows][128 cols], row-major, 32KB = exact lds fit.
  // prow = wave*16 + quad*4 + r, pcol = tt*16 + l15.
  {
    const int prowb = wave * 16 + quad * 4;
#pragma unroll
    for (int tt = 0; tt < 8; ++tt)
#pragma unroll
      for (int r = 0; r < 4; ++r)
        lds[(prowb + r) * 128 + tt * 16 + l15] = f2bf_bits(acc[tt][r]);
  }
  __syncthreads();
  // A-frags: wave owns head rows s0w = wave*16 + (0..15); lane row l15, k = kk*32+quad*8
  const unsigned short* prd = lds + (wave * 16 + l15) * 128 + quad * 8;
  bf8 paF[4];
#pragma unroll
  for (int kk = 0; kk < 4; ++kk) paF[kk] = ldb(prd + kk * 32);
  // B-frags: B[k=t][n=dk] = vst[b][dk][t]; lane: dk = ni*16+l15, t = t0c+kk*32+quad*8+j
  const unsigned short* vbb = vst + ((long)b * DK_ + l15) * S_ + t0c + quad * 8;
  f4 pacc[4];
#pragma unroll
  for (int ni = 0; ni < 4; ++ni) pacc[ni] = f4{0.f, 0.f, 0.f, 0.f};
#pragma unroll
  for (int ni = 0; ni < 4; ++ni)
#pragma unroll
    for (int kk = 0; kk < 4; ++kk) {
      bf8 bf = ldb(vbb + (long)(ni * 16) * S_ + kk * 32);
      pacc[ni] = MFMA(paF[kk], bf, pacc[ni]);
    }
  // C-layout: row = quad*4+r (rel to wave's 16), col dk = ni*16+l15
  const long rbase2 = (long)b * S_ + stile * 128 + wave * 16 + quad * 4;
#pragma unroll
  for (int ni = 0; ni < 4; ++ni)
#pragma unroll
    for (int r = 0; r < 4; ++r)
      atomicAdd(headf + (rbase2 + r) * 64 + ni * 16 + l15, pacc[ni][r]);
}

// ---- out = head @ Wo (head read as f32 from headf, cast inline) ----
// grid (8 d-chunks of 128, 32 s-tiles of 64, B), block 256
__global__ __launch_bounds__(256) void k_out(
    const float* __restrict__ headf, const unsigned short* __restrict__ wot,
    float* __restrict__ out) {
  const int tid = threadIdx.x, wave = tid >> 6, lane = tid & 63;
  const int l15 = lane & 15, quad = lane >> 4;
  const int dchunk = blockIdx.x, stile = blockIdx.y, b = blockIdx.z;
  const int s0 = stile * 64 + wave * 16;
  const int n0 = dchunk * 128;
  const float* hrow = headf + ((long)b * S_ + s0 + l15) * DK_ + quad * 8;
  f4 h0lo = *reinterpret_cast<const f4*>(hrow);
  f4 h0hi = *reinterpret_cast<const f4*>(hrow + 4);
  f4 h1lo = *reinterpret_cast<const f4*>(hrow + 32);
  f4 h1hi = *reinterpret_cast<const f4*>(hrow + 36);
  bf8 a0 = pack_bf8(h0lo, h0hi);
  bf8 a1 = pack_bf8(h1lo, h1hi);
  const unsigned short* wb = wot + quad * 8;
  float* obase = out + ((long)b * S_ + s0 + quad * 4) * D_ + n0 + l15;
#pragma unroll
  for (int i = 0; i < 8; ++i) {
    const unsigned short* wp = wb + (long)(n0 + i * 16 + l15) * DK_;
    bf8 b0 = ldb(wp);
    bf8 b1 = ldb(wp + 32);
    f4 d = f4{0.f, 0.f, 0.f, 0.f};
    d = MFMA(a0, b0, d);
    d = MFMA(a1, b1, d);
#pragma unroll
    for (int r = 0; r < 4; ++r) obase[(long)r * D_ + i * 16] = d[r];
  }
}

extern "C" void kernel_launch(void* const* d_in, const int* in_sizes, int n_in,
                              void* d_out, int out_size, void* d_ws, size_t ws_size,
                              hipStream_t stream) {
  const float* q  = (const float*)d_in[0];
  const float* k  = (const float*)d_in[1];
  const float* v  = (const float*)d_in[2];
  const float* Wq = (const float*)d_in[3];
  const float* Wk = (const float*)d_in[4];
  const float* Wv = (const float*)d_in[5];
  const float* Wo = (const float*)d_in[6];

  float* out = (float*)d_out;                       // [B,S,D] = 4,194,304 f32
  float* am  = out + (long)B_ * S_ * D_;            // [B,S,S] = 8,388,608 f32

  // workspace (~21.5 MB)
  unsigned short* qsb  = (unsigned short*)d_ws;     // [4096][1024]
  unsigned short* ksb  = qsb + 4194304;
  unsigned short* wqt  = ksb + 4194304;             // [1024][1024]
  unsigned short* wkt  = wqt + 1048576;
  unsigned short* wvt  = wkt + 1048576;             // [64][1024]
  unsigned short* wot  = wvt + 65536;               // [1024][64]
  unsigned short* vst  = wot + 65536;               // [B][64][S]
  unsigned short* headb= vst + 262144;              // (unused; kept for layout)
  float* recip = (float*)(headb + 262144);          // [B*H*S]

  // bf16 q,k copies live in the am region of d_out (dead before k_attn writes am)
  unsigned short* qb = (unsigned short*)am;         // [4096][1024]
  unsigned short* kb = qb + 4194304;
  // split-K f32 partials [4][4096][64] live in the out region (dead until k_out)
  float* part = out;
  // head f32 accumulator [4096][64] = 1MB lives in the wqt region (dead after k_qkpv;
  // zeroed by k_denomv's extra blocks; accumulated by k_attn's atomics; read by k_out)
  float* headf = (float*)wqt;

  k_prep<<<4384, 256, 0, stream>>>(q, k, Wq, Wk, Wv, Wo, qb, kb, wqt, wkt, wvt, wot);
  k_qkpv<<<768, 256, 0, stream>>>(qb, kb, wqt, wkt, qsb, ksb, v, wvt, part);
  k_denomv<<<1536, 512, 0, stream>>>(qsb, ksb, recip, part, vst, headf);
  k_attn<<<512, 512, 0, stream>>>(qsb, ksb, recip, am, vst, headf);
  k_out<<<dim3(8, 32, 2), 256, 0, stream>>>(headf, wot, out);
}